// Round 5
// baseline (213.777 us; speedup 1.0000x reference)
//
#include <hip/hip_runtime.h>
#include <math.h>

#define SS 2048
#define DD 1280
#define HH 16
#define HDD 80
#define ND3 3840
#define ZZ 2   // K-split factor for attention partials

typedef __attribute__((ext_vector_type(8))) short short8;
typedef __attribute__((ext_vector_type(4))) short s16x4;
typedef __attribute__((ext_vector_type(4))) float f32x4;
typedef __attribute__((ext_vector_type(8))) _Float16 h16x8;
typedef __attribute__((ext_vector_type(4))) _Float16 h16x4;

__device__ inline short f2bf(float f) {
    union { float f; unsigned u; } x; x.f = f;
    unsigned r = x.u + 0x7FFF + ((x.u >> 16) & 1);
    return (short)(r >> 16);
}

// direct global->LDS 16B staging (m97 pattern). LDS dest must be the
// wave-uniform base; HW adds lane*16.
__device__ inline void gload_lds16(const void* g, void* l) {
    __builtin_amdgcn_global_load_lds(
        (const __attribute__((address_space(1))) void*)g,
        (__attribute__((address_space(3))) void*)l, 16, 0, 0);
}

// ---------------- fused convert: three fp32 arrays -> fp16 ----------------
__global__ __launch_bounds__(256) void split_f16(
    const float* __restrict__ a, _Float16* __restrict__ ah, int nbA,
    const float* __restrict__ b, _Float16* __restrict__ bh, int nbB,
    const float* __restrict__ c, _Float16* __restrict__ ch)
{
    const float* x; _Float16* h;
    int blk = blockIdx.x;
    if (blk < nbA)            { x = a; h = ah; }
    else if (blk < nbA + nbB) { blk -= nbA; x = b; h = bh; }
    else                      { blk -= nbA + nbB; x = c; h = ch; }
    int i = (blk * 256 + threadIdx.x) * 4;
    float4 v = *(const float4*)(x + i);
    h16x4 hv;
    hv[0] = (_Float16)v.x; hv[1] = (_Float16)v.y;
    hv[2] = (_Float16)v.z; hv[3] = (_Float16)v.w;
    *(h16x4*)(h + i) = hv;
}

#define LDSA(m, kg) ((m) * 32 + (((kg) ^ (((m) >> 1) & 3)) << 3))

// ---------------- fp16 MFMA GEMM: C = A @ B^T + bias ----------------
// R14 == R13 resubmission (container failed twice; audit found no kernel
// defect — suspect infra). global_load_lds width-16 direct staging with
// pre-swizzled global source: linear slot i stores chunk kg=(i&3)^((i>>3)&3)
// so existing LDSA(m,quad) reads resolve correctly.
template <int BMT, int BNT>
__global__ __launch_bounds__(256) void gemm_f16(
    const _Float16* __restrict__ Ah, const _Float16* __restrict__ Bh,
    const float* __restrict__ bias, float* __restrict__ C,
    int M, int N, int K)
{
    constexpr int IT = BMT / 32;
    constexpr int JT = BNT / 32;
    constexpr int AU = BMT / 64;
    constexpr int BU = BNT / 64;
    __shared__ _Float16 AhS[BMT * 32];
    __shared__ _Float16 BhS[BNT * 32];

    const int tid = threadIdx.x;
    const int w = tid >> 6;
    const int lane = tid & 63;
    const int l15 = lane & 15;
    const int quad = lane >> 4;
    const int wm = w >> 1, wn = w & 1;
    const int bm = blockIdx.y * BMT;
    const int bn = blockIdx.x * BNT;

    f32x4 acc[IT][JT];
    #pragma unroll
    for (int i = 0; i < IT; ++i)
        #pragma unroll
        for (int j = 0; j < JT; ++j)
            acc[i][j] = (f32x4){0.f, 0.f, 0.f, 0.f};

    for (int k0 = 0; k0 < K; k0 += 32) {
        __syncthreads();
        #pragma unroll
        for (int u = 0; u < AU; ++u) {
            int i = tid + u * 256;
            int m = i >> 2;
            int kg = (i & 3) ^ ((m >> 1) & 3);
            gload_lds16(Ah + (size_t)(bm + m) * K + k0 + kg * 8,
                        &AhS[(i & ~63) * 8]);
        }
        #pragma unroll
        for (int u = 0; u < BU; ++u) {
            int i = tid + u * 256;
            int m = i >> 2;
            int kg = (i & 3) ^ ((m >> 1) & 3);
            gload_lds16(Bh + (size_t)(bn + m) * K + k0 + kg * 8,
                        &BhS[(i & ~63) * 8]);
        }
        __syncthreads();   // compiler drains vmcnt here

        h16x8 af[IT], bf[JT];
        #pragma unroll
        for (int i = 0; i < IT; ++i) {
            int m = wm * (BMT / 2) + i * 16 + l15;
            af[i] = *(h16x8*)&AhS[LDSA(m, quad)];
        }
        #pragma unroll
        for (int j = 0; j < JT; ++j) {
            int n = wn * (BNT / 2) + j * 16 + l15;
            bf[j] = *(h16x8*)&BhS[LDSA(n, quad)];
        }
        #pragma unroll
        for (int i = 0; i < IT; ++i)
            #pragma unroll
            for (int j = 0; j < JT; ++j)
                acc[i][j] = __builtin_amdgcn_mfma_f32_16x16x32_f16(af[i], bf[j], acc[i][j], 0, 0, 0);
    }

    #pragma unroll
    for (int j = 0; j < JT; ++j) {
        int col = bn + wn * (BNT / 2) + j * 16 + l15;
        float bb = bias[col];
        #pragma unroll
        for (int i = 0; i < IT; ++i)
            #pragma unroll
            for (int r = 0; r < 4; ++r) {
                int row = bm + wm * (BMT / 2) + i * 16 + quad * 4 + r;
                C[(size_t)row * N + col] = acc[i][j][r] + bb;
            }
    }
}

// ---- proj GEMM with fused attention-merge in A-staging (ZZ=2 partials) ----
// B side staged via global_load_lds (pre-swizzled source); A side keeps
// reg-prefetch (needs VALU merge before LDS write).
__global__ __launch_bounds__(256) void gemm_proj_merge(
    const _Float16* __restrict__ o_part, const float* __restrict__ l_part,
    const _Float16* __restrict__ Bh,
    const float* __restrict__ bias, float* __restrict__ C,
    int M, int N, int K)
{
    constexpr int BMT = 64, BNT = 128;
    constexpr int JT = BNT / 32;
    constexpr int BU = BNT / 64;
    __shared__ _Float16 AhS[BMT * 32];
    __shared__ _Float16 BhS[BNT * 32];
    __shared__ float linvS[HH * 64];

    const int tid = threadIdx.x;
    const int w = tid >> 6;
    const int lane = tid & 63;
    const int l15 = lane & 15;
    const int quad = lane >> 4;
    const int wm = w >> 1, wn = w & 1;
    const int bm = blockIdx.y * BMT;
    const int bn = blockIdx.x * BNT;

    // build inv-l table: 16 heads x 64 rows, summed over ZZ partials
    for (int i = tid; i < HH * 64; i += 256) {
        int h = i >> 6, r = i & 63;
        float ls = 0.f;
        #pragma unroll
        for (int zi = 0; zi < ZZ; ++zi)
            ls += l_part[((size_t)zi * HH + h) * SS + bm + r];
        linvS[i] = 1.f / ls;
    }

    f32x4 acc[2][JT];
    #pragma unroll
    for (int i = 0; i < 2; ++i)
        #pragma unroll
        for (int j = 0; j < JT; ++j)
            acc[i][j] = (f32x4){0.f, 0.f, 0.f, 0.f};

    h16x8 ra[ZZ];
    auto loadgA = [&](int k0) {
        int m = tid >> 2, kg = tid & 3;
        size_t off = (size_t)(bm + m) * K + k0 + kg * 8;
        #pragma unroll
        for (int zi = 0; zi < ZZ; ++zi)
            ra[zi] = *(const h16x8*)(o_part + (size_t)zi * SS * DD + off);
    };

    loadgA(0);
    for (int k0 = 0; k0 < K; k0 += 32) {
        __syncthreads();
        {
            int m = tid >> 2, kg = tid & 3;
            int koff = k0 + kg * 8;
            int h = koff / HDD;                 // 8-elem chunk stays in one head
            float inv = linvS[h * 64 + m];
            h16x8 f;
            #pragma unroll
            for (int e = 0; e < 8; ++e) {
                float s = (float)ra[0][e];
                #pragma unroll
                for (int zi = 1; zi < ZZ; ++zi) s += (float)ra[zi][e];
                f[e] = (_Float16)(s * inv);
            }
            *(h16x8*)&AhS[LDSA(m, kg)] = f;
        }
        #pragma unroll
        for (int u = 0; u < BU; ++u) {
            int i = tid + u * 256;
            int m = i >> 2;
            int kg = (i & 3) ^ ((m >> 1) & 3);
            gload_lds16(Bh + (size_t)(bn + m) * K + k0 + kg * 8,
                        &BhS[(i & ~63) * 8]);
        }
        __syncthreads();
        if (k0 + 32 < K) loadgA(k0 + 32);

        h16x8 af[2], bf[JT];
        #pragma unroll
        for (int i = 0; i < 2; ++i) {
            int m = wm * 32 + i * 16 + l15;
            af[i] = *(h16x8*)&AhS[LDSA(m, quad)];
        }
        #pragma unroll
        for (int j = 0; j < JT; ++j) {
            int n = wn * 64 + j * 16 + l15;
            bf[j] = *(h16x8*)&BhS[LDSA(n, quad)];
        }
        #pragma unroll
        for (int i = 0; i < 2; ++i)
            #pragma unroll
            for (int j = 0; j < JT; ++j)
                acc[i][j] = __builtin_amdgcn_mfma_f32_16x16x32_f16(af[i], bf[j], acc[i][j], 0, 0, 0);
    }

    #pragma unroll
    for (int j = 0; j < JT; ++j) {
        int col = bn + wn * 64 + j * 16 + l15;
        float bb = bias[col];
        #pragma unroll
        for (int i = 0; i < 2; ++i)
            #pragma unroll
            for (int r = 0; r < 4; ++r) {
                int row = bm + wm * 32 + i * 16 + quad * 4 + r;
                C[(size_t)row * N + col] = acc[i][j][r] + bb;
            }
    }
}

// ---------------- RoPE + scatter, 4-wide vectorized ----------------
__global__ __launch_bounds__(256) void rope_scatter_bf16(
    const float* __restrict__ qkv, const float* __restrict__ rpe,
    short* __restrict__ q, short* __restrict__ k, short* __restrict__ v)
{
    __shared__ __align__(16) float cs[40], sn[40];
    const int s = blockIdx.x;
    if (threadIdx.x < 40)
        __sincosf(rpe[s * 40 + threadIdx.x], &sn[threadIdx.x], &cs[threadIdx.x]);
    __syncthreads();
    const float scale = 0.11180339887498949f;  // 80^-0.5
    const float* src = qkv + (size_t)s * ND3;
    for (int t = threadIdx.x; t < ND3 / 4; t += 256) {
        int j4 = t * 4;
        int p = j4 / DD;
        int rem = j4 - p * DD;
        int hh = rem / HDD;
        int d = rem - hh * HDD;
        float4 x = *(const float4*)(src + j4);
        float vv[4];
        if (p == 2) {
            vv[0] = x.x; vv[1] = x.y; vv[2] = x.z; vv[3] = x.w;
        } else {
            bool lo = d < 40;
            int dm = lo ? d : d - 40;
            float4 oth = *(const float4*)(src + p * DD + hh * HDD + (lo ? d + 40 : d - 40));
            float4 c4 = *(const float4*)&cs[dm];
            float4 s4 = *(const float4*)&sn[dm];
            float sg = lo ? -1.f : 1.f;
            vv[0] = x.x * c4.x + sg * oth.x * s4.x;
            vv[1] = x.y * c4.y + sg * oth.y * s4.y;
            vv[2] = x.z * c4.z + sg * oth.z * s4.z;
            vv[3] = x.w * c4.w + sg * oth.w * s4.w;
            if (p == 0) { vv[0] *= scale; vv[1] *= scale; vv[2] *= scale; vv[3] *= scale; }
        }
        short* dst = (p == 0) ? q : (p == 1) ? k : v;
        s16x4 o4;
        o4[0] = f2bf(vv[0]); o4[1] = f2bf(vv[1]);
        o4[2] = f2bf(vv[2]); o4[3] = f2bf(vv[3]);
        *(s16x4*)(dst + ((size_t)hh * SS + s) * HDD + d) = o4;
    }
}

// ---- flash attention: 8 waves x 16 q-rows (512 threads), z=2 (R12) ----
__global__ __launch_bounds__(512, 4) void attn_mfma(
    const short* __restrict__ q, const short* __restrict__ k,
    const short* __restrict__ v, _Float16* __restrict__ o_part,
    float* __restrict__ l_part)
{
    __shared__ short Ks[64][104];     // keys x dims (pad cols 80..95 zeroed)
    __shared__ short Vts[80 * 64];    // dims x keys, XOR-swizzled octets
    __shared__ short Ps[8][16 * 64];  // per-wave P tile, XOR octet swizzle

    const int h = blockIdx.y;
    const int q0 = blockIdx.x << 7;   // 128 rows per block
    const int z = blockIdx.z;
    const int tid = threadIdx.x;
    const int w = tid >> 6;           // 0..7
    const int lane = tid & 63;
    const int l15 = lane & 15;
    const int quad = lane >> 4;

    const short* qbase = q + (size_t)h * SS * HDD;
    const short* kbase = k + (size_t)h * SS * HDD;
    const short* vbase = v + (size_t)h * SS * HDD;

    short8 qf[3];
    {
        const int row = q0 + w * 16 + l15;
        #pragma unroll
        for (int kk = 0; kk < 3; ++kk) {
            int c0 = kk * 32 + quad * 8;
            qf[kk] = (c0 < HDD) ? *(const short8*)(qbase + (size_t)row * HDD + c0)
                                : (short8)0;
        }
    }

    if (tid < 128) {   // zero K pad cols 80..95
        int r = tid >> 1, c = 80 + (tid & 1) * 8;
        *(short8*)&Ks[r][c] = (short8)0;
    }

    float lsum[4] = {0.f, 0.f, 0.f, 0.f};
    f32x4 o[5];
    #pragma unroll
    for (int n = 0; n < 5; ++n) o[n] = (f32x4){0.f, 0.f, 0.f, 0.f};

    const int kt0 = z << 10;          // 1024 kv rows per z-slice
    for (int kt = kt0; kt < kt0 + 1024; kt += 64) {
        __syncthreads();
        #pragma unroll
        for (int u = 0; u < 2; ++u) {
            int i = tid + u * 512;
            if (i < 640) {
                int r = i / 10, c = (i - r * 10) * 8;
                *(short8*)&Ks[r][c] = *(const short8*)(kbase + (size_t)(kt + r) * HDD + c);
            }
        }
        {
            int task = tid;
            if (task < 320) {
                int r4 = (task & 15) << 2;
                int d4 = (task >> 4) << 2;
                s16x4 a0 = *(const s16x4*)(vbase + (size_t)(kt + r4 + 0) * HDD + d4);
                s16x4 a1 = *(const s16x4*)(vbase + (size_t)(kt + r4 + 1) * HDD + d4);
                s16x4 a2 = *(const s16x4*)(vbase + (size_t)(kt + r4 + 2) * HDD + d4);
                s16x4 a3 = *(const s16x4*)(vbase + (size_t)(kt + r4 + 3) * HDD + d4);
                #pragma unroll
                for (int j = 0; j < 4; ++j) {
                    s16x4 w4 = {a0[j], a1[j], a2[j], a3[j]};
                    int d = d4 + j;
                    int sw = (r4 >> 3) ^ (d & 7);
                    *(s16x4*)&Vts[d * 64 + sw * 8 + (r4 & 7)] = w4;
                }
            }
        }
        __syncthreads();

        f32x4 s_[4];
        #pragma unroll
        for (int nt = 0; nt < 4; ++nt) {
            short8 bf0 = *(short8*)&Ks[nt * 16 + l15][quad * 8];
            short8 bf1 = *(short8*)&Ks[nt * 16 + l15][32 + quad * 8];
            short8 bf2 = *(short8*)&Ks[nt * 16 + l15][64 + quad * 8];
            f32x4 acc = (f32x4){0.f, 0.f, 0.f, 0.f};
            acc = __builtin_amdgcn_mfma_f32_16x16x32_bf16(qf[0], bf0, acc, 0, 0, 0);
            acc = __builtin_amdgcn_mfma_f32_16x16x32_bf16(qf[1], bf1, acc, 0, 0, 0);
            acc = __builtin_amdgcn_mfma_f32_16x16x32_bf16(qf[2], bf2, acc, 0, 0, 0);
            s_[nt] = acc;
        }

        // Ps write: logical (row, col) -> phys row*64 + ((col>>3 ^ row&7)<<3) + (col&7)
        #pragma unroll
        for (int nt = 0; nt < 4; ++nt)
            #pragma unroll
            for (int r = 0; r < 4; ++r) {
                float p = __expf(s_[nt][r] - 8.f);
                lsum[r] += p;
                int row = quad * 4 + r;
                int g = (nt * 2 + (l15 >> 3)) ^ (row & 7);
                Ps[w][row * 64 + g * 8 + (l15 & 7)] = f2bf(p);
            }

        short8 pf[2];
        #pragma unroll
        for (int kk = 0; kk < 2; ++kk) {
            int g = (kk * 4 + quad) ^ (l15 & 7);
            pf[kk] = *(short8*)&Ps[w][l15 * 64 + g * 8];
        }
        #pragma unroll
        for (int n = 0; n < 5; ++n) {
            #pragma unroll
            for (int kk = 0; kk < 2; ++kk) {
                int d = n * 16 + l15;
                int sw = (kk * 4 + quad) ^ (l15 & 7);
                short8 vf = *(short8*)&Vts[d * 64 + sw * 8];
                o[n] = __builtin_amdgcn_mfma_f32_16x16x32_bf16(pf[kk], vf, o[n], 0, 0, 0);
            }
        }
    }

    _Float16* ob = o_part + (size_t)z * SS * DD;
    #pragma unroll
    for (int r = 0; r < 4; ++r) {
        float rs = lsum[r];
        #pragma unroll
        for (int off = 1; off < 16; off <<= 1)
            rs += __shfl_xor(rs, off, 64);
        lsum[r] = rs;
    }
    #pragma unroll
    for (int n = 0; n < 5; ++n)
        #pragma unroll
        for (int r = 0; r < 4; ++r) {
            int row = q0 + w * 16 + quad * 4 + r;
            ob[(size_t)row * DD + h * HDD + n * 16 + l15] = (_Float16)o[n][r];
        }
    if (l15 == 0)
        #pragma unroll
        for (int r = 0; r < 4; ++r)
            l_part[((size_t)z * HH + h) * SS + q0 + w * 16 + quad * 4 + r] = lsum[r];
}

extern "C" void kernel_launch(void* const* d_in, const int* in_sizes, int n_in,
                              void* d_out, int out_size, void* d_ws, size_t ws_size,
                              hipStream_t stream)
{
    const float* hs     = (const float*)d_in[0];
    const float* rpe    = (const float*)d_in[1];
    const float* qkv_w  = (const float*)d_in[2];
    const float* qkv_b  = (const float*)d_in[3];
    const float* proj_w = (const float*)d_in[4];
    const float* proj_b = (const float*)d_in[5];
    float* out = (float*)d_out;

    // ---- workspace layout (55.7 MB, region-aliased; 2-byte units) ----
    short* s0 = (short*)d_ws;                   // R0: 15,728,640 units
    float* qkv_f  = (float*)d_ws;               //   [S][3D] fp32, dead after rope
    _Float16* o_part = (_Float16*)s0;           //   R0 reuse: ZZ x S x D fp16 partials
    float* l_part = (float*)(s0 + 10485760);    //   ZZ x H x S fp32
    short* s1 = s0 + 15728640;                  // R1: 7,864,320 units
    _Float16* qkvw_h = (_Float16*)s1;           //   dead after gemm1
    short* qb = s1;                             //   R1 reuse after gemm1
    short* kb = s1 + 2621440;
    short* vb = s1 + 5242880;
    short* s2 = s1 + 7864320;                   // R2: 2,621,440 units
    _Float16* hs_h = (_Float16*)s2;
    short* s3 = s2 + 2621440;                   // R3: 1,638,400 units
    _Float16* projw_h = (_Float16*)s3;

    const int n_hs = SS * DD;        // 2,621,440 -> 2560 blocks
    const int n_qw = ND3 * DD;       // 4,915,200 -> 4800 blocks
    const int n_pw = DD * DD;        // 1,638,400 -> 1600 blocks

    split_f16<<<n_hs / 1024 + n_qw / 1024 + n_pw / 1024, 256, 0, stream>>>(
        hs, hs_h, n_hs / 1024,
        qkv_w, qkvw_h, n_qw / 1024,
        proj_w, projw_h);
    gemm_f16<128, 128><<<dim3(ND3 / 128, SS / 128), 256, 0, stream>>>(
        hs_h, qkvw_h, qkv_b, qkv_f, SS, ND3, DD);
    rope_scatter_bf16<<<SS, 256, 0, stream>>>(qkv_f, rpe, qb, kb, vb);
    attn_mfma<<<dim3(SS / 128, HH, ZZ), 512, 0, stream>>>(qb, kb, vb, o_part, l_part);
    gemm_proj_merge<<<dim3(DD / 128, SS / 64), 256, 0, stream>>>(
        o_part, l_part, projw_h, proj_b, out, SS, DD, DD);
}

// Round 6
// 211.196 us; speedup vs baseline: 1.0122x; 1.0122x over previous
//
#include <hip/hip_runtime.h>
#include <math.h>

#define SS 2048
#define DD 1280
#define HH 16
#define HDD 80
#define ND3 3840
#define ZZ 2   // K-split factor for attention partials

typedef __attribute__((ext_vector_type(8))) short short8;
typedef __attribute__((ext_vector_type(4))) short s16x4;
typedef __attribute__((ext_vector_type(4))) float f32x4;
typedef __attribute__((ext_vector_type(8))) _Float16 h16x8;
typedef __attribute__((ext_vector_type(4))) _Float16 h16x4;

__device__ inline short f2bf(float f) {
    union { float f; unsigned u; } x; x.f = f;
    unsigned r = x.u + 0x7FFF + ((x.u >> 16) & 1);
    return (short)(r >> 16);
}

// direct global->LDS 16B staging (m97 pattern). LDS dest must be the
// wave-uniform base; HW adds lane*16.
__device__ inline void gload_lds16(const void* g, void* l) {
    __builtin_amdgcn_global_load_lds(
        (const __attribute__((address_space(1))) void*)g,
        (__attribute__((address_space(3))) void*)l, 16, 0, 0);
}

// ---------------- fused convert: three fp32 arrays -> fp16 ----------------
__global__ __launch_bounds__(256) void split_f16(
    const float* __restrict__ a, _Float16* __restrict__ ah, int nbA,
    const float* __restrict__ b, _Float16* __restrict__ bh, int nbB,
    const float* __restrict__ c, _Float16* __restrict__ ch)
{
    const float* x; _Float16* h;
    int blk = blockIdx.x;
    if (blk < nbA)            { x = a; h = ah; }
    else if (blk < nbA + nbB) { blk -= nbA; x = b; h = bh; }
    else                      { blk -= nbA + nbB; x = c; h = ch; }
    int i = (blk * 256 + threadIdx.x) * 4;
    float4 v = *(const float4*)(x + i);
    h16x4 hv;
    hv[0] = (_Float16)v.x; hv[1] = (_Float16)v.y;
    hv[2] = (_Float16)v.z; hv[3] = (_Float16)v.w;
    *(h16x4*)(h + i) = hv;
}

#define LDSA(m, kg) ((m) * 32 + (((kg) ^ (((m) >> 1) & 3)) << 3))

// ---------------- fp16 MFMA GEMM: C = A @ B^T + bias ----------------
// R15: T3 minimum-2-phase pipeline. Double-buffered LDS; per K-step:
// issue next tile's global_load_lds FIRST, ds_read+MFMA current buffer,
// then ONE __syncthreads (its vmcnt(0) drain = the wait for the next
// tile, which flew during compute). R13's version drained vmcnt before
// compute -> exposed latency; this overlaps it.
template <int BMT, int BNT>
__global__ __launch_bounds__(256) void gemm_f16(
    const _Float16* __restrict__ Ah, const _Float16* __restrict__ Bh,
    const float* __restrict__ bias, float* __restrict__ C,
    int M, int N, int K)
{
    constexpr int IT = BMT / 32;
    constexpr int JT = BNT / 32;
    constexpr int AU = BMT / 64;
    constexpr int BU = BNT / 64;
    __shared__ _Float16 AhS[2][BMT * 32];
    __shared__ _Float16 BhS[2][BNT * 32];

    const int tid = threadIdx.x;
    const int w = tid >> 6;
    const int lane = tid & 63;
    const int l15 = lane & 15;
    const int quad = lane >> 4;
    const int wm = w >> 1, wn = w & 1;
    const int bm = blockIdx.y * BMT;
    const int bn = blockIdx.x * BNT;

    f32x4 acc[IT][JT];
    #pragma unroll
    for (int i = 0; i < IT; ++i)
        #pragma unroll
        for (int j = 0; j < JT; ++j)
            acc[i][j] = (f32x4){0.f, 0.f, 0.f, 0.f};

    auto stage = [&](int buf, int k0) {
        #pragma unroll
        for (int u = 0; u < AU; ++u) {
            int i = tid + u * 256;
            int m = i >> 2;
            int kg = (i & 3) ^ ((m >> 1) & 3);
            gload_lds16(Ah + (size_t)(bm + m) * K + k0 + kg * 8,
                        &AhS[buf][(i & ~63) * 8]);
        }
        #pragma unroll
        for (int u = 0; u < BU; ++u) {
            int i = tid + u * 256;
            int m = i >> 2;
            int kg = (i & 3) ^ ((m >> 1) & 3);
            gload_lds16(Bh + (size_t)(bn + m) * K + k0 + kg * 8,
                        &BhS[buf][(i & ~63) * 8]);
        }
    };

    stage(0, 0);
    __syncthreads();            // drain prologue stage
    int cur = 0;
    for (int k0 = 0; k0 < K; k0 += 32) {
        if (k0 + 32 < K) stage(cur ^ 1, k0 + 32);   // issue next, no wait

        h16x8 af[IT], bf[JT];
        #pragma unroll
        for (int i = 0; i < IT; ++i) {
            int m = wm * (BMT / 2) + i * 16 + l15;
            af[i] = *(h16x8*)&AhS[cur][LDSA(m, quad)];
        }
        #pragma unroll
        for (int j = 0; j < JT; ++j) {
            int n = wn * (BNT / 2) + j * 16 + l15;
            bf[j] = *(h16x8*)&BhS[cur][LDSA(n, quad)];
        }
        #pragma unroll
        for (int i = 0; i < IT; ++i)
            #pragma unroll
            for (int j = 0; j < JT; ++j)
                acc[i][j] = __builtin_amdgcn_mfma_f32_16x16x32_f16(af[i], bf[j], acc[i][j], 0, 0, 0);

        __syncthreads();        // drains vmcnt(0): next tile now resident
        cur ^= 1;
    }

    #pragma unroll
    for (int j = 0; j < JT; ++j) {
        int col = bn + wn * (BNT / 2) + j * 16 + l15;
        float bb = bias[col];
        #pragma unroll
        for (int i = 0; i < IT; ++i)
            #pragma unroll
            for (int r = 0; r < 4; ++r) {
                int row = bm + wm * (BMT / 2) + i * 16 + quad * 4 + r;
                C[(size_t)row * N + col] = acc[i][j][r] + bb;
            }
    }
}

// ---- proj GEMM with fused attention-merge in A-staging (ZZ=2 partials) ----
// R15: B double-buffered via global_load_lds issued AFTER the A-visibility
// barrier, draining at the post-MFMA barrier (overlaps compute). A keeps
// reg-prefetch (merge VALU), issued before MFMA so it also overlaps.
__global__ __launch_bounds__(256) void gemm_proj_merge(
    const _Float16* __restrict__ o_part, const float* __restrict__ l_part,
    const _Float16* __restrict__ Bh,
    const float* __restrict__ bias, float* __restrict__ C,
    int M, int N, int K)
{
    constexpr int BMT = 64, BNT = 128;
    constexpr int JT = BNT / 32;
    constexpr int BU = BNT / 64;
    __shared__ _Float16 AhS[BMT * 32];
    __shared__ _Float16 BhS[2][BNT * 32];
    __shared__ float linvS[HH * 64];

    const int tid = threadIdx.x;
    const int w = tid >> 6;
    const int lane = tid & 63;
    const int l15 = lane & 15;
    const int quad = lane >> 4;
    const int wm = w >> 1, wn = w & 1;
    const int bm = blockIdx.y * BMT;
    const int bn = blockIdx.x * BNT;

    // build inv-l table: 16 heads x 64 rows, summed over ZZ partials
    for (int i = tid; i < HH * 64; i += 256) {
        int h = i >> 6, r = i & 63;
        float ls = 0.f;
        #pragma unroll
        for (int zi = 0; zi < ZZ; ++zi)
            ls += l_part[((size_t)zi * HH + h) * SS + bm + r];
        linvS[i] = 1.f / ls;
    }

    f32x4 acc[2][JT];
    #pragma unroll
    for (int i = 0; i < 2; ++i)
        #pragma unroll
        for (int j = 0; j < JT; ++j)
            acc[i][j] = (f32x4){0.f, 0.f, 0.f, 0.f};

    h16x8 ra[ZZ];
    auto loadgA = [&](int k0) {
        int m = tid >> 2, kg = tid & 3;
        size_t off = (size_t)(bm + m) * K + k0 + kg * 8;
        #pragma unroll
        for (int zi = 0; zi < ZZ; ++zi)
            ra[zi] = *(const h16x8*)(o_part + (size_t)zi * SS * DD + off);
    };
    auto stageB = [&](int buf, int k0) {
        #pragma unroll
        for (int u = 0; u < BU; ++u) {
            int i = tid + u * 256;
            int m = i >> 2;
            int kg = (i & 3) ^ ((m >> 1) & 3);
            gload_lds16(Bh + (size_t)(bn + m) * K + k0 + kg * 8,
                        &BhS[buf][(i & ~63) * 8]);
        }
    };

    stageB(0, 0);
    loadgA(0);
    __syncthreads();            // linv + B0 resident
    int cur = 0;
    for (int k0 = 0; k0 < K; k0 += 32) {
        {   // merge A partials -> fp16 LDS (consumes prefetched ra)
            int m = tid >> 2, kg = tid & 3;
            int koff = k0 + kg * 8;
            int h = koff / HDD;                 // 8-elem chunk stays in one head
            float inv = linvS[h * 64 + m];
            h16x8 f;
            #pragma unroll
            for (int e = 0; e < 8; ++e) {
                float s = (float)ra[0][e];
                #pragma unroll
                for (int zi = 1; zi < ZZ; ++zi) s += (float)ra[zi][e];
                f[e] = (_Float16)(s * inv);
            }
            *(h16x8*)&AhS[LDSA(m, kg)] = f;
        }
        __syncthreads();        // A visible (no pending async B yet)

        if (k0 + 32 < K) {
            stageB(cur ^ 1, k0 + 32);   // async, flies during MFMA
            loadgA(k0 + 32);            // reg prefetch, flies during MFMA
        }

        h16x8 af[2], bf[JT];
        #pragma unroll
        for (int i = 0; i < 2; ++i) {
            int m = wm * 32 + i * 16 + l15;
            af[i] = *(h16x8*)&AhS[LDSA(m, quad)];
        }
        #pragma unroll
        for (int j = 0; j < JT; ++j) {
            int n = wn * 64 + j * 16 + l15;
            bf[j] = *(h16x8*)&BhS[cur][LDSA(n, quad)];
        }
        #pragma unroll
        for (int i = 0; i < 2; ++i)
            #pragma unroll
            for (int j = 0; j < JT; ++j)
                acc[i][j] = __builtin_amdgcn_mfma_f32_16x16x32_f16(af[i], bf[j], acc[i][j], 0, 0, 0);

        __syncthreads();        // drains next-B loads; frees AhS + BhS[cur]
        cur ^= 1;
    }

    #pragma unroll
    for (int j = 0; j < JT; ++j) {
        int col = bn + wn * 64 + j * 16 + l15;
        float bb = bias[col];
        #pragma unroll
        for (int i = 0; i < 2; ++i)
            #pragma unroll
            for (int r = 0; r < 4; ++r) {
                int row = bm + wm * 32 + i * 16 + quad * 4 + r;
                C[(size_t)row * N + col] = acc[i][j][r] + bb;
            }
    }
}

// ---------------- RoPE + scatter, 4-wide vectorized ----------------
__global__ __launch_bounds__(256) void rope_scatter_bf16(
    const float* __restrict__ qkv, const float* __restrict__ rpe,
    short* __restrict__ q, short* __restrict__ k, short* __restrict__ v)
{
    __shared__ __align__(16) float cs[40], sn[40];
    const int s = blockIdx.x;
    if (threadIdx.x < 40)
        __sincosf(rpe[s * 40 + threadIdx.x], &sn[threadIdx.x], &cs[threadIdx.x]);
    __syncthreads();
    const float scale = 0.11180339887498949f;  // 80^-0.5
    const float* src = qkv + (size_t)s * ND3;
    for (int t = threadIdx.x; t < ND3 / 4; t += 256) {
        int j4 = t * 4;
        int p = j4 / DD;
        int rem = j4 - p * DD;
        int hh = rem / HDD;
        int d = rem - hh * HDD;
        float4 x = *(const float4*)(src + j4);
        float vv[4];
        if (p == 2) {
            vv[0] = x.x; vv[1] = x.y; vv[2] = x.z; vv[3] = x.w;
        } else {
            bool lo = d < 40;
            int dm = lo ? d : d - 40;
            float4 oth = *(const float4*)(src + p * DD + hh * HDD + (lo ? d + 40 : d - 40));
            float4 c4 = *(const float4*)&cs[dm];
            float4 s4 = *(const float4*)&sn[dm];
            float sg = lo ? -1.f : 1.f;
            vv[0] = x.x * c4.x + sg * oth.x * s4.x;
            vv[1] = x.y * c4.y + sg * oth.y * s4.y;
            vv[2] = x.z * c4.z + sg * oth.z * s4.z;
            vv[3] = x.w * c4.w + sg * oth.w * s4.w;
            if (p == 0) { vv[0] *= scale; vv[1] *= scale; vv[2] *= scale; vv[3] *= scale; }
        }
        short* dst = (p == 0) ? q : (p == 1) ? k : v;
        s16x4 o4;
        o4[0] = f2bf(vv[0]); o4[1] = f2bf(vv[1]);
        o4[2] = f2bf(vv[2]); o4[3] = f2bf(vv[3]);
        *(s16x4*)(dst + ((size_t)hh * SS + s) * HDD + d) = o4;
    }
}

// ---- flash attention: 8 waves x 16 q-rows (512 threads), z=2 (R12) ----
__global__ __launch_bounds__(512, 4) void attn_mfma(
    const short* __restrict__ q, const short* __restrict__ k,
    const short* __restrict__ v, _Float16* __restrict__ o_part,
    float* __restrict__ l_part)
{
    __shared__ short Ks[64][104];     // keys x dims (pad cols 80..95 zeroed)
    __shared__ short Vts[80 * 64];    // dims x keys, XOR-swizzled octets
    __shared__ short Ps[8][16 * 64];  // per-wave P tile, XOR octet swizzle

    const int h = blockIdx.y;
    const int q0 = blockIdx.x << 7;   // 128 rows per block
    const int z = blockIdx.z;
    const int tid = threadIdx.x;
    const int w = tid >> 6;           // 0..7
    const int lane = tid & 63;
    const int l15 = lane & 15;
    const int quad = lane >> 4;

    const short* qbase = q + (size_t)h * SS * HDD;
    const short* kbase = k + (size_t)h * SS * HDD;
    const short* vbase = v + (size_t)h * SS * HDD;

    short8 qf[3];
    {
        const int row = q0 + w * 16 + l15;
        #pragma unroll
        for (int kk = 0; kk < 3; ++kk) {
            int c0 = kk * 32 + quad * 8;
            qf[kk] = (c0 < HDD) ? *(const short8*)(qbase + (size_t)row * HDD + c0)
                                : (short8)0;
        }
    }

    if (tid < 128) {   // zero K pad cols 80..95
        int r = tid >> 1, c = 80 + (tid & 1) * 8;
        *(short8*)&Ks[r][c] = (short8)0;
    }

    float lsum[4] = {0.f, 0.f, 0.f, 0.f};
    f32x4 o[5];
    #pragma unroll
    for (int n = 0; n < 5; ++n) o[n] = (f32x4){0.f, 0.f, 0.f, 0.f};

    const int kt0 = z << 10;          // 1024 kv rows per z-slice
    for (int kt = kt0; kt < kt0 + 1024; kt += 64) {
        __syncthreads();
        #pragma unroll
        for (int u = 0; u < 2; ++u) {
            int i = tid + u * 512;
            if (i < 640) {
                int r = i / 10, c = (i - r * 10) * 8;
                *(short8*)&Ks[r][c] = *(const short8*)(kbase + (size_t)(kt + r) * HDD + c);
            }
        }
        {
            int task = tid;
            if (task < 320) {
                int r4 = (task & 15) << 2;
                int d4 = (task >> 4) << 2;
                s16x4 a0 = *(const s16x4*)(vbase + (size_t)(kt + r4 + 0) * HDD + d4);
                s16x4 a1 = *(const s16x4*)(vbase + (size_t)(kt + r4 + 1) * HDD + d4);
                s16x4 a2 = *(const s16x4*)(vbase + (size_t)(kt + r4 + 2) * HDD + d4);
                s16x4 a3 = *(const s16x4*)(vbase + (size_t)(kt + r4 + 3) * HDD + d4);
                #pragma unroll
                for (int j = 0; j < 4; ++j) {
                    s16x4 w4 = {a0[j], a1[j], a2[j], a3[j]};
                    int d = d4 + j;
                    int sw = (r4 >> 3) ^ (d & 7);
                    *(s16x4*)&Vts[d * 64 + sw * 8 + (r4 & 7)] = w4;
                }
            }
        }
        __syncthreads();

        f32x4 s_[4];
        #pragma unroll
        for (int nt = 0; nt < 4; ++nt) {
            short8 bf0 = *(short8*)&Ks[nt * 16 + l15][quad * 8];
            short8 bf1 = *(short8*)&Ks[nt * 16 + l15][32 + quad * 8];
            short8 bf2 = *(short8*)&Ks[nt * 16 + l15][64 + quad * 8];
            f32x4 acc = (f32x4){0.f, 0.f, 0.f, 0.f};
            acc = __builtin_amdgcn_mfma_f32_16x16x32_bf16(qf[0], bf0, acc, 0, 0, 0);
            acc = __builtin_amdgcn_mfma_f32_16x16x32_bf16(qf[1], bf1, acc, 0, 0, 0);
            acc = __builtin_amdgcn_mfma_f32_16x16x32_bf16(qf[2], bf2, acc, 0, 0, 0);
            s_[nt] = acc;
        }

        // Ps write: logical (row, col) -> phys row*64 + ((col>>3 ^ row&7)<<3) + (col&7)
        #pragma unroll
        for (int nt = 0; nt < 4; ++nt)
            #pragma unroll
            for (int r = 0; r < 4; ++r) {
                float p = __expf(s_[nt][r] - 8.f);
                lsum[r] += p;
                int row = quad * 4 + r;
                int g = (nt * 2 + (l15 >> 3)) ^ (row & 7);
                Ps[w][row * 64 + g * 8 + (l15 & 7)] = f2bf(p);
            }

        short8 pf[2];
        #pragma unroll
        for (int kk = 0; kk < 2; ++kk) {
            int g = (kk * 4 + quad) ^ (l15 & 7);
            pf[kk] = *(short8*)&Ps[w][l15 * 64 + g * 8];
        }
        #pragma unroll
        for (int n = 0; n < 5; ++n) {
            #pragma unroll
            for (int kk = 0; kk < 2; ++kk) {
                int d = n * 16 + l15;
                int sw = (kk * 4 + quad) ^ (l15 & 7);
                short8 vf = *(short8*)&Vts[d * 64 + sw * 8];
                o[n] = __builtin_amdgcn_mfma_f32_16x16x32_bf16(pf[kk], vf, o[n], 0, 0, 0);
            }
        }
    }

    _Float16* ob = o_part + (size_t)z * SS * DD;
    #pragma unroll
    for (int r = 0; r < 4; ++r) {
        float rs = lsum[r];
        #pragma unroll
        for (int off = 1; off < 16; off <<= 1)
            rs += __shfl_xor(rs, off, 64);
        lsum[r] = rs;
    }
    #pragma unroll
    for (int n = 0; n < 5; ++n)
        #pragma unroll
        for (int r = 0; r < 4; ++r) {
            int row = q0 + w * 16 + quad * 4 + r;
            ob[(size_t)row * DD + h * HDD + n * 16 + l15] = (_Float16)o[n][r];
        }
    if (l15 == 0)
        #pragma unroll
        for (int r = 0; r < 4; ++r)
            l_part[((size_t)z * HH + h) * SS + q0 + w * 16 + quad * 4 + r] = lsum[r];
}

extern "C" void kernel_launch(void* const* d_in, const int* in_sizes, int n_in,
                              void* d_out, int out_size, void* d_ws, size_t ws_size,
                              hipStream_t stream)
{
    const float* hs     = (const float*)d_in[0];
    const float* rpe    = (const float*)d_in[1];
    const float* qkv_w  = (const float*)d_in[2];
    const float* qkv_b  = (const float*)d_in[3];
    const float* proj_w = (const float*)d_in[4];
    const float* proj_b = (const float*)d_in[5];
    float* out = (float*)d_out;

    // ---- workspace layout (55.7 MB, region-aliased; 2-byte units) ----
    short* s0 = (short*)d_ws;                   // R0: 15,728,640 units
    float* qkv_f  = (float*)d_ws;               //   [S][3D] fp32, dead after rope
    _Float16* o_part = (_Float16*)s0;           //   R0 reuse: ZZ x S x D fp16 partials
    float* l_part = (float*)(s0 + 10485760);    //   ZZ x H x S fp32
    short* s1 = s0 + 15728640;                  // R1: 7,864,320 units
    _Float16* qkvw_h = (_Float16*)s1;           //   dead after gemm1
    short* qb = s1;                             //   R1 reuse after gemm1
    short* kb = s1 + 2621440;
    short* vb = s1 + 5242880;
    short* s2 = s1 + 7864320;                   // R2: 2,621,440 units
    _Float16* hs_h = (_Float16*)s2;
    short* s3 = s2 + 2621440;                   // R3: 1,638,400 units
    _Float16* projw_h = (_Float16*)s3;

    const int n_hs = SS * DD;        // 2,621,440 -> 2560 blocks
    const int n_qw = ND3 * DD;       // 4,915,200 -> 4800 blocks
    const int n_pw = DD * DD;        // 1,638,400 -> 1600 blocks

    split_f16<<<n_hs / 1024 + n_qw / 1024 + n_pw / 1024, 256, 0, stream>>>(
        hs, hs_h, n_hs / 1024,
        qkv_w, qkvw_h, n_qw / 1024,
        proj_w, projw_h);
    gemm_f16<128, 128><<<dim3(ND3 / 128, SS / 128), 256, 0, stream>>>(
        hs_h, qkvw_h, qkv_b, qkv_f, SS, ND3, DD);
    rope_scatter_bf16<<<SS, 256, 0, stream>>>(qkv_f, rpe, qb, kb, vb);
    attn_mfma<<<dim3(SS / 128, HH, ZZ), 512, 0, stream>>>(qb, kb, vb, o_part, l_part);
    gemm_proj_merge<<<dim3(DD / 128, SS / 64), 256, 0, stream>>>(
        o_part, l_part, projw_h, proj_b, out, SS, DD, DD);
}

// Round 7
// 206.525 us; speedup vs baseline: 1.0351x; 1.0226x over previous
//
#include <hip/hip_runtime.h>
#include <math.h>

#define SS 2048
#define DD 1280
#define HH 16
#define HDD 80
#define ND3 3840
#define ZZ 2   // K-split factor for attention partials

typedef __attribute__((ext_vector_type(8))) short short8;
typedef __attribute__((ext_vector_type(4))) short s16x4;
typedef __attribute__((ext_vector_type(4))) float f32x4;
typedef __attribute__((ext_vector_type(8))) _Float16 h16x8;
typedef __attribute__((ext_vector_type(4))) _Float16 h16x4;

__device__ inline short f2bf(float f) {
    union { float f; unsigned u; } x; x.f = f;
    unsigned r = x.u + 0x7FFF + ((x.u >> 16) & 1);
    return (short)(r >> 16);
}

// direct global->LDS 16B staging (m97 pattern). LDS dest must be the
// wave-uniform base; HW adds lane*16.
__device__ inline void gload_lds16(const void* g, void* l) {
    __builtin_amdgcn_global_load_lds(
        (const __attribute__((address_space(1))) void*)g,
        (__attribute__((address_space(3))) void*)l, 16, 0, 0);
}

// ---------------- fused convert: three fp32 arrays -> fp16 ----------------
__global__ __launch_bounds__(256) void split_f16(
    const float* __restrict__ a, _Float16* __restrict__ ah, int nbA,
    const float* __restrict__ b, _Float16* __restrict__ bh, int nbB,
    const float* __restrict__ c, _Float16* __restrict__ ch)
{
    const float* x; _Float16* h;
    int blk = blockIdx.x;
    if (blk < nbA)            { x = a; h = ah; }
    else if (blk < nbA + nbB) { blk -= nbA; x = b; h = bh; }
    else                      { blk -= nbA + nbB; x = c; h = ch; }
    int i = (blk * 256 + threadIdx.x) * 4;
    float4 v = *(const float4*)(x + i);
    h16x4 hv;
    hv[0] = (_Float16)v.x; hv[1] = (_Float16)v.y;
    hv[2] = (_Float16)v.z; hv[3] = (_Float16)v.w;
    *(h16x4*)(h + i) = hv;
}

#define LDSA(m, kg) ((m) * 32 + (((kg) ^ (((m) >> 1) & 3)) << 3))

// ---------------- fp16 MFMA GEMM: C = A @ B^T + bias (R15 2-phase) --------
template <int BMT, int BNT>
__global__ __launch_bounds__(256) void gemm_f16(
    const _Float16* __restrict__ Ah, const _Float16* __restrict__ Bh,
    const float* __restrict__ bias, float* __restrict__ C,
    int M, int N, int K)
{
    constexpr int IT = BMT / 32;
    constexpr int JT = BNT / 32;
    constexpr int AU = BMT / 64;
    constexpr int BU = BNT / 64;
    __shared__ _Float16 AhS[2][BMT * 32];
    __shared__ _Float16 BhS[2][BNT * 32];

    const int tid = threadIdx.x;
    const int w = tid >> 6;
    const int lane = tid & 63;
    const int l15 = lane & 15;
    const int quad = lane >> 4;
    const int wm = w >> 1, wn = w & 1;
    const int bm = blockIdx.y * BMT;
    const int bn = blockIdx.x * BNT;

    f32x4 acc[IT][JT];
    #pragma unroll
    for (int i = 0; i < IT; ++i)
        #pragma unroll
        for (int j = 0; j < JT; ++j)
            acc[i][j] = (f32x4){0.f, 0.f, 0.f, 0.f};

    auto stage = [&](int buf, int k0) {
        #pragma unroll
        for (int u = 0; u < AU; ++u) {
            int i = tid + u * 256;
            int m = i >> 2;
            int kg = (i & 3) ^ ((m >> 1) & 3);
            gload_lds16(Ah + (size_t)(bm + m) * K + k0 + kg * 8,
                        &AhS[buf][(i & ~63) * 8]);
        }
        #pragma unroll
        for (int u = 0; u < BU; ++u) {
            int i = tid + u * 256;
            int m = i >> 2;
            int kg = (i & 3) ^ ((m >> 1) & 3);
            gload_lds16(Bh + (size_t)(bn + m) * K + k0 + kg * 8,
                        &BhS[buf][(i & ~63) * 8]);
        }
    };

    stage(0, 0);
    __syncthreads();            // drain prologue stage
    int cur = 0;
    for (int k0 = 0; k0 < K; k0 += 32) {
        if (k0 + 32 < K) stage(cur ^ 1, k0 + 32);   // issue next, no wait

        h16x8 af[IT], bf[JT];
        #pragma unroll
        for (int i = 0; i < IT; ++i) {
            int m = wm * (BMT / 2) + i * 16 + l15;
            af[i] = *(h16x8*)&AhS[cur][LDSA(m, quad)];
        }
        #pragma unroll
        for (int j = 0; j < JT; ++j) {
            int n = wn * (BNT / 2) + j * 16 + l15;
            bf[j] = *(h16x8*)&BhS[cur][LDSA(n, quad)];
        }
        #pragma unroll
        for (int i = 0; i < IT; ++i)
            #pragma unroll
            for (int j = 0; j < JT; ++j)
                acc[i][j] = __builtin_amdgcn_mfma_f32_16x16x32_f16(af[i], bf[j], acc[i][j], 0, 0, 0);

        __syncthreads();        // drains vmcnt(0): next tile now resident
        cur ^= 1;
    }

    #pragma unroll
    for (int j = 0; j < JT; ++j) {
        int col = bn + wn * (BNT / 2) + j * 16 + l15;
        float bb = bias[col];
        #pragma unroll
        for (int i = 0; i < IT; ++i)
            #pragma unroll
            for (int r = 0; r < 4; ++r) {
                int row = bm + wm * (BMT / 2) + i * 16 + quad * 4 + r;
                C[(size_t)row * N + col] = acc[i][j][r] + bb;
            }
    }
}

// ---- proj GEMM with fused attention-merge in A-staging (R15 2-phase B) ----
__global__ __launch_bounds__(256) void gemm_proj_merge(
    const _Float16* __restrict__ o_part, const float* __restrict__ l_part,
    const _Float16* __restrict__ Bh,
    const float* __restrict__ bias, float* __restrict__ C,
    int M, int N, int K)
{
    constexpr int BMT = 64, BNT = 128;
    constexpr int JT = BNT / 32;
    constexpr int BU = BNT / 64;
    __shared__ _Float16 AhS[BMT * 32];
    __shared__ _Float16 BhS[2][BNT * 32];
    __shared__ float linvS[HH * 64];

    const int tid = threadIdx.x;
    const int w = tid >> 6;
    const int lane = tid & 63;
    const int l15 = lane & 15;
    const int quad = lane >> 4;
    const int wm = w >> 1, wn = w & 1;
    const int bm = blockIdx.y * BMT;
    const int bn = blockIdx.x * BNT;

    // build inv-l table: 16 heads x 64 rows, summed over ZZ partials
    for (int i = tid; i < HH * 64; i += 256) {
        int h = i >> 6, r = i & 63;
        float ls = 0.f;
        #pragma unroll
        for (int zi = 0; zi < ZZ; ++zi)
            ls += l_part[((size_t)zi * HH + h) * SS + bm + r];
        linvS[i] = 1.f / ls;
    }

    f32x4 acc[2][JT];
    #pragma unroll
    for (int i = 0; i < 2; ++i)
        #pragma unroll
        for (int j = 0; j < JT; ++j)
            acc[i][j] = (f32x4){0.f, 0.f, 0.f, 0.f};

    h16x8 ra[ZZ];
    auto loadgA = [&](int k0) {
        int m = tid >> 2, kg = tid & 3;
        size_t off = (size_t)(bm + m) * K + k0 + kg * 8;
        #pragma unroll
        for (int zi = 0; zi < ZZ; ++zi)
            ra[zi] = *(const h16x8*)(o_part + (size_t)zi * SS * DD + off);
    };
    auto stageB = [&](int buf, int k0) {
        #pragma unroll
        for (int u = 0; u < BU; ++u) {
            int i = tid + u * 256;
            int m = i >> 2;
            int kg = (i & 3) ^ ((m >> 1) & 3);
            gload_lds16(Bh + (size_t)(bn + m) * K + k0 + kg * 8,
                        &BhS[buf][(i & ~63) * 8]);
        }
    };

    stageB(0, 0);
    loadgA(0);
    __syncthreads();            // linv + B0 resident
    int cur = 0;
    for (int k0 = 0; k0 < K; k0 += 32) {
        {   // merge A partials -> fp16 LDS (consumes prefetched ra)
            int m = tid >> 2, kg = tid & 3;
            int koff = k0 + kg * 8;
            int h = koff / HDD;                 // 8-elem chunk stays in one head
            float inv = linvS[h * 64 + m];
            h16x8 f;
            #pragma unroll
            for (int e = 0; e < 8; ++e) {
                float s = (float)ra[0][e];
                #pragma unroll
                for (int zi = 1; zi < ZZ; ++zi) s += (float)ra[zi][e];
                f[e] = (_Float16)(s * inv);
            }
            *(h16x8*)&AhS[LDSA(m, kg)] = f;
        }
        __syncthreads();        // A visible (no pending async B yet)

        if (k0 + 32 < K) {
            stageB(cur ^ 1, k0 + 32);   // async, flies during MFMA
            loadgA(k0 + 32);            // reg prefetch, flies during MFMA
        }

        h16x8 af[2], bf[JT];
        #pragma unroll
        for (int i = 0; i < 2; ++i) {
            int m = wm * 32 + i * 16 + l15;
            af[i] = *(h16x8*)&AhS[LDSA(m, quad)];
        }
        #pragma unroll
        for (int j = 0; j < JT; ++j) {
            int n = wn * 64 + j * 16 + l15;
            bf[j] = *(h16x8*)&BhS[cur][LDSA(n, quad)];
        }
        #pragma unroll
        for (int i = 0; i < 2; ++i)
            #pragma unroll
            for (int j = 0; j < JT; ++j)
                acc[i][j] = __builtin_amdgcn_mfma_f32_16x16x32_f16(af[i], bf[j], acc[i][j], 0, 0, 0);

        __syncthreads();        // drains next-B loads; frees AhS + BhS[cur]
        cur ^= 1;
    }

    #pragma unroll
    for (int j = 0; j < JT; ++j) {
        int col = bn + wn * 64 + j * 16 + l15;
        float bb = bias[col];
        #pragma unroll
        for (int i = 0; i < 2; ++i)
            #pragma unroll
            for (int r = 0; r < 4; ++r) {
                int row = bm + wm * 32 + i * 16 + quad * 4 + r;
                C[(size_t)row * N + col] = acc[i][j][r] + bb;
            }
    }
}

// ---------------- RoPE + scatter, 4-wide vectorized ----------------
__global__ __launch_bounds__(256) void rope_scatter_bf16(
    const float* __restrict__ qkv, const float* __restrict__ rpe,
    short* __restrict__ q, short* __restrict__ k, short* __restrict__ v)
{
    __shared__ __align__(16) float cs[40], sn[40];
    const int s = blockIdx.x;
    if (threadIdx.x < 40)
        __sincosf(rpe[s * 40 + threadIdx.x], &sn[threadIdx.x], &cs[threadIdx.x]);
    __syncthreads();
    const float scale = 0.11180339887498949f;  // 80^-0.5
    const float* src = qkv + (size_t)s * ND3;
    for (int t = threadIdx.x; t < ND3 / 4; t += 256) {
        int j4 = t * 4;
        int p = j4 / DD;
        int rem = j4 - p * DD;
        int hh = rem / HDD;
        int d = rem - hh * HDD;
        float4 x = *(const float4*)(src + j4);
        float vv[4];
        if (p == 2) {
            vv[0] = x.x; vv[1] = x.y; vv[2] = x.z; vv[3] = x.w;
        } else {
            bool lo = d < 40;
            int dm = lo ? d : d - 40;
            float4 oth = *(const float4*)(src + p * DD + hh * HDD + (lo ? d + 40 : d - 40));
            float4 c4 = *(const float4*)&cs[dm];
            float4 s4 = *(const float4*)&sn[dm];
            float sg = lo ? -1.f : 1.f;
            vv[0] = x.x * c4.x + sg * oth.x * s4.x;
            vv[1] = x.y * c4.y + sg * oth.y * s4.y;
            vv[2] = x.z * c4.z + sg * oth.z * s4.z;
            vv[3] = x.w * c4.w + sg * oth.w * s4.w;
            if (p == 0) { vv[0] *= scale; vv[1] *= scale; vv[2] *= scale; vv[3] *= scale; }
        }
        short* dst = (p == 0) ? q : (p == 1) ? k : v;
        s16x4 o4;
        o4[0] = f2bf(vv[0]); o4[1] = f2bf(vv[1]);
        o4[2] = f2bf(vv[2]); o4[3] = f2bf(vv[3]);
        *(s16x4*)(dst + ((size_t)hh * SS + s) * HDD + d) = o4;
    }
}

// ---- flash attention: 8 waves x 16 q-rows, z=2 ----
// R16 delta (T14 async-STAGE + T5 setprio):
//  - double-buffered Ks/Vts (63.5 KB LDS total, still 2 blocks/CU);
//  - per tile: ISSUE next tile's global loads BEFORE compute, WRITE regs->
//    LDS after compute (vmcnt resolved under QK+softmax+PV), ONE barrier
//    per tile (was 2 + exposed latency);
//  - s_setprio(1) around both MFMA clusters (m191: attn-positive).
__global__ __launch_bounds__(512, 4) void attn_mfma(
    const short* __restrict__ q, const short* __restrict__ k,
    const short* __restrict__ v, _Float16* __restrict__ o_part,
    float* __restrict__ l_part)
{
    __shared__ short Ks[2][64][104];   // keys x dims (pad cols 80..95 zeroed)
    __shared__ short Vts[2][80 * 64];  // dims x keys, XOR-swizzled octets
    __shared__ short Ps[8][16 * 64];   // per-wave P tile, XOR octet swizzle

    const int h = blockIdx.y;
    const int q0 = blockIdx.x << 7;   // 128 rows per block
    const int z = blockIdx.z;
    const int tid = threadIdx.x;
    const int w = tid >> 6;           // 0..7
    const int lane = tid & 63;
    const int l15 = lane & 15;
    const int quad = lane >> 4;

    const short* qbase = q + (size_t)h * SS * HDD;
    const short* kbase = k + (size_t)h * SS * HDD;
    const short* vbase = v + (size_t)h * SS * HDD;

    short8 qf[3];
    {
        const int row = q0 + w * 16 + l15;
        #pragma unroll
        for (int kk = 0; kk < 3; ++kk) {
            int c0 = kk * 32 + quad * 8;
            qf[kk] = (c0 < HDD) ? *(const short8*)(qbase + (size_t)row * HDD + c0)
                                : (short8)0;
        }
    }

    if (tid < 256) {   // zero K pad cols 80..95 in BOTH buffers (never rewritten)
        int b = tid >> 7;
        int t2 = tid & 127;
        int r = t2 >> 1, c = 80 + (t2 & 1) * 8;
        *(short8*)&Ks[b][r][c] = (short8)0;
    }

    float lsum[4] = {0.f, 0.f, 0.f, 0.f};
    f32x4 o[5];
    #pragma unroll
    for (int n = 0; n < 5; ++n) o[n] = (f32x4){0.f, 0.f, 0.f, 0.f};

    // ---- async-stage state: K (2x short8), V (4x s16x4) ----
    short8 kr[2];
    s16x4 vr[4];
    auto issueKV = [&](int kt) {
        #pragma unroll
        for (int u = 0; u < 2; ++u) {
            int i = tid + u * 512;
            if (i < 640) {
                int r = i / 10, c = (i - r * 10) * 8;
                kr[u] = *(const short8*)(kbase + (size_t)(kt + r) * HDD + c);
            }
        }
        if (tid < 320) {
            int r4 = (tid & 15) << 2, d4 = (tid >> 4) << 2;
            #pragma unroll
            for (int j = 0; j < 4; ++j)
                vr[j] = *(const s16x4*)(vbase + (size_t)(kt + r4 + j) * HDD + d4);
        }
    };
    auto writeKV = [&](int buf) {
        #pragma unroll
        for (int u = 0; u < 2; ++u) {
            int i = tid + u * 512;
            if (i < 640) {
                int r = i / 10, c = (i - r * 10) * 8;
                *(short8*)&Ks[buf][r][c] = kr[u];
            }
        }
        if (tid < 320) {
            int r4 = (tid & 15) << 2, d4 = (tid >> 4) << 2;
            #pragma unroll
            for (int j = 0; j < 4; ++j) {
                s16x4 w4 = {vr[0][j], vr[1][j], vr[2][j], vr[3][j]};
                int d = d4 + j;
                int sw = (r4 >> 3) ^ (d & 7);
                *(s16x4*)&Vts[buf][d * 64 + sw * 8 + (r4 & 7)] = w4;
            }
        }
    };

    const int kt0 = z << 10;          // 1024 kv rows per z-slice
    issueKV(kt0);
    writeKV(0);
    __syncthreads();
    int cur = 0;
    for (int t = 0; t < 16; ++t) {
        const int kt = kt0 + t * 64;
        const bool more = (t + 1 < 16);
        if (more) issueKV(kt + 64);    // VMEM in flight across compute

        f32x4 s_[4];
        __builtin_amdgcn_s_setprio(1);
        #pragma unroll
        for (int nt = 0; nt < 4; ++nt) {
            short8 bf0 = *(short8*)&Ks[cur][nt * 16 + l15][quad * 8];
            short8 bf1 = *(short8*)&Ks[cur][nt * 16 + l15][32 + quad * 8];
            short8 bf2 = *(short8*)&Ks[cur][nt * 16 + l15][64 + quad * 8];
            f32x4 acc = (f32x4){0.f, 0.f, 0.f, 0.f};
            acc = __builtin_amdgcn_mfma_f32_16x16x32_bf16(qf[0], bf0, acc, 0, 0, 0);
            acc = __builtin_amdgcn_mfma_f32_16x16x32_bf16(qf[1], bf1, acc, 0, 0, 0);
            acc = __builtin_amdgcn_mfma_f32_16x16x32_bf16(qf[2], bf2, acc, 0, 0, 0);
            s_[nt] = acc;
        }
        __builtin_amdgcn_s_setprio(0);

        // Ps write: logical (row, col) -> phys row*64 + ((col>>3 ^ row&7)<<3) + (col&7)
        #pragma unroll
        for (int nt = 0; nt < 4; ++nt)
            #pragma unroll
            for (int r = 0; r < 4; ++r) {
                float p = __expf(s_[nt][r] - 8.f);
                lsum[r] += p;
                int row = quad * 4 + r;
                int g = (nt * 2 + (l15 >> 3)) ^ (row & 7);
                Ps[w][row * 64 + g * 8 + (l15 & 7)] = f2bf(p);
            }

        short8 pf[2];
        #pragma unroll
        for (int kk = 0; kk < 2; ++kk) {
            int g = (kk * 4 + quad) ^ (l15 & 7);
            pf[kk] = *(short8*)&Ps[w][l15 * 64 + g * 8];
        }
        __builtin_amdgcn_s_setprio(1);
        #pragma unroll
        for (int n = 0; n < 5; ++n) {
            #pragma unroll
            for (int kk = 0; kk < 2; ++kk) {
                int d = n * 16 + l15;
                int sw = (kk * 4 + quad) ^ (l15 & 7);
                short8 vf = *(short8*)&Vts[cur][d * 64 + sw * 8];
                o[n] = __builtin_amdgcn_mfma_f32_16x16x32_bf16(pf[kk], vf, o[n], 0, 0, 0);
            }
        }
        __builtin_amdgcn_s_setprio(0);

        if (more) writeKV(cur ^ 1);    // vmcnt naturally resolved by now
        __syncthreads();               // buf[cur^1] visible; reads of buf[cur] done
        cur ^= 1;
    }

    _Float16* ob = o_part + (size_t)z * SS * DD;
    #pragma unroll
    for (int r = 0; r < 4; ++r) {
        float rs = lsum[r];
        #pragma unroll
        for (int off = 1; off < 16; off <<= 1)
            rs += __shfl_xor(rs, off, 64);
        lsum[r] = rs;
    }
    #pragma unroll
    for (int n = 0; n < 5; ++n)
        #pragma unroll
        for (int r = 0; r < 4; ++r) {
            int row = q0 + w * 16 + quad * 4 + r;
            ob[(size_t)row * DD + h * HDD + n * 16 + l15] = (_Float16)o[n][r];
        }
    if (l15 == 0)
        #pragma unroll
        for (int r = 0; r < 4; ++r)
            l_part[((size_t)z * HH + h) * SS + q0 + w * 16 + quad * 4 + r] = lsum[r];
}

extern "C" void kernel_launch(void* const* d_in, const int* in_sizes, int n_in,
                              void* d_out, int out_size, void* d_ws, size_t ws_size,
                              hipStream_t stream)
{
    const float* hs     = (const float*)d_in[0];
    const float* rpe    = (const float*)d_in[1];
    const float* qkv_w  = (const float*)d_in[2];
    const float* qkv_b  = (const float*)d_in[3];
    const float* proj_w = (const float*)d_in[4];
    const float* proj_b = (const float*)d_in[5];
    float* out = (float*)d_out;

    // ---- workspace layout (55.7 MB, region-aliased; 2-byte units) ----
    short* s0 = (short*)d_ws;                   // R0: 15,728,640 units
    float* qkv_f  = (float*)d_ws;               //   [S][3D] fp32, dead after rope
    _Float16* o_part = (_Float16*)s0;           //   R0 reuse: ZZ x S x D fp16 partials
    float* l_part = (float*)(s0 + 10485760);    //   ZZ x H x S fp32
    short* s1 = s0 + 15728640;                  // R1: 7,864,320 units
    _Float16* qkvw_h = (_Float16*)s1;           //   dead after gemm1
    short* qb = s1;                             //   R1 reuse after gemm1
    short* kb = s1 + 2621440;
    short* vb = s1 + 5242880;
    short* s2 = s1 + 7864320;                   // R2: 2,621,440 units
    _Float16* hs_h = (_Float16*)s2;
    short* s3 = s2 + 2621440;                   // R3: 1,638,400 units
    _Float16* projw_h = (_Float16*)s3;

    const int n_hs = SS * DD;        // 2,621,440 -> 2560 blocks
    const int n_qw = ND3 * DD;       // 4,915,200 -> 4800 blocks
    const int n_pw = DD * DD;        // 1,638,400 -> 1600 blocks

    split_f16<<<n_hs / 1024 + n_qw / 1024 + n_pw / 1024, 256, 0, stream>>>(
        hs, hs_h, n_hs / 1024,
        qkv_w, qkvw_h, n_qw / 1024,
        proj_w, projw_h);
    gemm_f16<128, 128><<<dim3(ND3 / 128, SS / 128), 256, 0, stream>>>(
        hs_h, qkvw_h, qkv_b, qkv_f, SS, ND3, DD);
    rope_scatter_bf16<<<SS, 256, 0, stream>>>(qkv_f, rpe, qb, kb, vb);
    attn_mfma<<<dim3(SS / 128, HH, ZZ), 512, 0, stream>>>(qb, kb, vb, o_part, l_part);
    gemm_proj_merge<<<dim3(DD / 128, SS / 64), 256, 0, stream>>>(
        o_part, l_part, projw_h, proj_b, out, SS, DD, DD);
}

// Round 8
// 206.137 us; speedup vs baseline: 1.0371x; 1.0019x over previous
//
#include <hip/hip_runtime.h>
#include <math.h>

#define SS 2048
#define DD 1280
#define HH 16
#define HDD 80
#define ND3 3840
#define ZZ 2   // K-split factor for attention partials

typedef __attribute__((ext_vector_type(8))) short short8;
typedef __attribute__((ext_vector_type(4))) short s16x4;
typedef __attribute__((ext_vector_type(4))) float f32x4;
typedef __attribute__((ext_vector_type(8))) _Float16 h16x8;
typedef __attribute__((ext_vector_type(4))) _Float16 h16x4;

__device__ inline short f2bf(float f) {
    union { float f; unsigned u; } x; x.f = f;
    unsigned r = x.u + 0x7FFF + ((x.u >> 16) & 1);
    return (short)(r >> 16);
}

// direct global->LDS 16B staging (m97 pattern). LDS dest must be the
// wave-uniform base; HW adds lane*16.
__device__ inline void gload_lds16(const void* g, void* l) {
    __builtin_amdgcn_global_load_lds(
        (const __attribute__((address_space(1))) void*)g,
        (__attribute__((address_space(3))) void*)l, 16, 0, 0);
}

// ---------------- fused convert: three fp32 arrays -> fp16 ----------------
__global__ __launch_bounds__(256) void split_f16(
    const float* __restrict__ a, _Float16* __restrict__ ah, int nbA,
    const float* __restrict__ b, _Float16* __restrict__ bh, int nbB,
    const float* __restrict__ c, _Float16* __restrict__ ch)
{
    const float* x; _Float16* h;
    int blk = blockIdx.x;
    if (blk < nbA)            { x = a; h = ah; }
    else if (blk < nbA + nbB) { blk -= nbA; x = b; h = bh; }
    else                      { blk -= nbA + nbB; x = c; h = ch; }
    int i = (blk * 256 + threadIdx.x) * 4;
    float4 v = *(const float4*)(x + i);
    h16x4 hv;
    hv[0] = (_Float16)v.x; hv[1] = (_Float16)v.y;
    hv[2] = (_Float16)v.z; hv[3] = (_Float16)v.w;
    *(h16x4*)(h + i) = hv;
}

#define LDSA(m, kg) ((m) * 32 + (((kg) ^ (((m) >> 1) & 3)) << 3))

// ---------------- fp16 MFMA GEMM: C = A @ B^T + bias (R15 2-phase) --------
template <int BMT, int BNT>
__global__ __launch_bounds__(256) void gemm_f16(
    const _Float16* __restrict__ Ah, const _Float16* __restrict__ Bh,
    const float* __restrict__ bias, float* __restrict__ C,
    int M, int N, int K)
{
    constexpr int IT = BMT / 32;
    constexpr int JT = BNT / 32;
    constexpr int AU = BMT / 64;
    constexpr int BU = BNT / 64;
    __shared__ _Float16 AhS[2][BMT * 32];
    __shared__ _Float16 BhS[2][BNT * 32];

    const int tid = threadIdx.x;
    const int w = tid >> 6;
    const int lane = tid & 63;
    const int l15 = lane & 15;
    const int quad = lane >> 4;
    const int wm = w >> 1, wn = w & 1;
    const int bm = blockIdx.y * BMT;
    const int bn = blockIdx.x * BNT;

    f32x4 acc[IT][JT];
    #pragma unroll
    for (int i = 0; i < IT; ++i)
        #pragma unroll
        for (int j = 0; j < JT; ++j)
            acc[i][j] = (f32x4){0.f, 0.f, 0.f, 0.f};

    auto stage = [&](int buf, int k0) {
        #pragma unroll
        for (int u = 0; u < AU; ++u) {
            int i = tid + u * 256;
            int m = i >> 2;
            int kg = (i & 3) ^ ((m >> 1) & 3);
            gload_lds16(Ah + (size_t)(bm + m) * K + k0 + kg * 8,
                        &AhS[buf][(i & ~63) * 8]);
        }
        #pragma unroll
        for (int u = 0; u < BU; ++u) {
            int i = tid + u * 256;
            int m = i >> 2;
            int kg = (i & 3) ^ ((m >> 1) & 3);
            gload_lds16(Bh + (size_t)(bn + m) * K + k0 + kg * 8,
                        &BhS[buf][(i & ~63) * 8]);
        }
    };

    stage(0, 0);
    __syncthreads();            // drain prologue stage
    int cur = 0;
    for (int k0 = 0; k0 < K; k0 += 32) {
        if (k0 + 32 < K) stage(cur ^ 1, k0 + 32);   // issue next, no wait

        h16x8 af[IT], bf[JT];
        #pragma unroll
        for (int i = 0; i < IT; ++i) {
            int m = wm * (BMT / 2) + i * 16 + l15;
            af[i] = *(h16x8*)&AhS[cur][LDSA(m, quad)];
        }
        #pragma unroll
        for (int j = 0; j < JT; ++j) {
            int n = wn * (BNT / 2) + j * 16 + l15;
            bf[j] = *(h16x8*)&BhS[cur][LDSA(n, quad)];
        }
        #pragma unroll
        for (int i = 0; i < IT; ++i)
            #pragma unroll
            for (int j = 0; j < JT; ++j)
                acc[i][j] = __builtin_amdgcn_mfma_f32_16x16x32_f16(af[i], bf[j], acc[i][j], 0, 0, 0);

        __syncthreads();        // drains vmcnt(0): next tile now resident
        cur ^= 1;
    }

    #pragma unroll
    for (int j = 0; j < JT; ++j) {
        int col = bn + wn * (BNT / 2) + j * 16 + l15;
        float bb = bias[col];
        #pragma unroll
        for (int i = 0; i < IT; ++i)
            #pragma unroll
            for (int r = 0; r < 4; ++r) {
                int row = bm + wm * (BMT / 2) + i * 16 + quad * 4 + r;
                C[(size_t)row * N + col] = acc[i][j][r] + bb;
            }
    }
}

// ---- proj GEMM with fused attention-merge in A-staging (R15 2-phase B) ----
__global__ __launch_bounds__(256) void gemm_proj_merge(
    const _Float16* __restrict__ o_part, const float* __restrict__ l_part,
    const _Float16* __restrict__ Bh,
    const float* __restrict__ bias, float* __restrict__ C,
    int M, int N, int K)
{
    constexpr int BMT = 64, BNT = 128;
    constexpr int JT = BNT / 32;
    constexpr int BU = BNT / 64;
    __shared__ _Float16 AhS[BMT * 32];
    __shared__ _Float16 BhS[2][BNT * 32];
    __shared__ float linvS[HH * 64];

    const int tid = threadIdx.x;
    const int w = tid >> 6;
    const int lane = tid & 63;
    const int l15 = lane & 15;
    const int quad = lane >> 4;
    const int wm = w >> 1, wn = w & 1;
    const int bm = blockIdx.y * BMT;
    const int bn = blockIdx.x * BNT;

    // build inv-l table: 16 heads x 64 rows, summed over ZZ partials
    for (int i = tid; i < HH * 64; i += 256) {
        int h = i >> 6, r = i & 63;
        float ls = 0.f;
        #pragma unroll
        for (int zi = 0; zi < ZZ; ++zi)
            ls += l_part[((size_t)zi * HH + h) * SS + bm + r];
        linvS[i] = 1.f / ls;
    }

    f32x4 acc[2][JT];
    #pragma unroll
    for (int i = 0; i < 2; ++i)
        #pragma unroll
        for (int j = 0; j < JT; ++j)
            acc[i][j] = (f32x4){0.f, 0.f, 0.f, 0.f};

    h16x8 ra[ZZ];
    auto loadgA = [&](int k0) {
        int m = tid >> 2, kg = tid & 3;
        size_t off = (size_t)(bm + m) * K + k0 + kg * 8;
        #pragma unroll
        for (int zi = 0; zi < ZZ; ++zi)
            ra[zi] = *(const h16x8*)(o_part + (size_t)zi * SS * DD + off);
    };
    auto stageB = [&](int buf, int k0) {
        #pragma unroll
        for (int u = 0; u < BU; ++u) {
            int i = tid + u * 256;
            int m = i >> 2;
            int kg = (i & 3) ^ ((m >> 1) & 3);
            gload_lds16(Bh + (size_t)(bn + m) * K + k0 + kg * 8,
                        &BhS[buf][(i & ~63) * 8]);
        }
    };

    stageB(0, 0);
    loadgA(0);
    __syncthreads();            // linv + B0 resident
    int cur = 0;
    for (int k0 = 0; k0 < K; k0 += 32) {
        {   // merge A partials -> fp16 LDS (consumes prefetched ra)
            int m = tid >> 2, kg = tid & 3;
            int koff = k0 + kg * 8;
            int h = koff / HDD;                 // 8-elem chunk stays in one head
            float inv = linvS[h * 64 + m];
            h16x8 f;
            #pragma unroll
            for (int e = 0; e < 8; ++e) {
                float s = (float)ra[0][e];
                #pragma unroll
                for (int zi = 1; zi < ZZ; ++zi) s += (float)ra[zi][e];
                f[e] = (_Float16)(s * inv);
            }
            *(h16x8*)&AhS[LDSA(m, kg)] = f;
        }
        __syncthreads();        // A visible (no pending async B yet)

        if (k0 + 32 < K) {
            stageB(cur ^ 1, k0 + 32);   // async, flies during MFMA
            loadgA(k0 + 32);            // reg prefetch, flies during MFMA
        }

        h16x8 af[2], bf[JT];
        #pragma unroll
        for (int i = 0; i < 2; ++i) {
            int m = wm * 32 + i * 16 + l15;
            af[i] = *(h16x8*)&AhS[LDSA(m, quad)];
        }
        #pragma unroll
        for (int j = 0; j < JT; ++j) {
            int n = wn * 64 + j * 16 + l15;
            bf[j] = *(h16x8*)&BhS[cur][LDSA(n, quad)];
        }
        #pragma unroll
        for (int i = 0; i < 2; ++i)
            #pragma unroll
            for (int j = 0; j < JT; ++j)
                acc[i][j] = __builtin_amdgcn_mfma_f32_16x16x32_f16(af[i], bf[j], acc[i][j], 0, 0, 0);

        __syncthreads();        // drains next-B loads; frees AhS + BhS[cur]
        cur ^= 1;
    }

    #pragma unroll
    for (int j = 0; j < JT; ++j) {
        int col = bn + wn * 64 + j * 16 + l15;
        float bb = bias[col];
        #pragma unroll
        for (int i = 0; i < 2; ++i)
            #pragma unroll
            for (int r = 0; r < 4; ++r) {
                int row = bm + wm * 32 + i * 16 + quad * 4 + r;
                C[(size_t)row * N + col] = acc[i][j][r] + bb;
            }
    }
}

// ---------------- RoPE + scatter, 4-wide vectorized ----------------
__global__ __launch_bounds__(256) void rope_scatter_bf16(
    const float* __restrict__ qkv, const float* __restrict__ rpe,
    short* __restrict__ q, short* __restrict__ k, short* __restrict__ v)
{
    __shared__ __align__(16) float cs[40], sn[40];
    const int s = blockIdx.x;
    if (threadIdx.x < 40)
        __sincosf(rpe[s * 40 + threadIdx.x], &sn[threadIdx.x], &cs[threadIdx.x]);
    __syncthreads();
    const float scale = 0.11180339887498949f;  // 80^-0.5
    const float* src = qkv + (size_t)s * ND3;
    for (int t = threadIdx.x; t < ND3 / 4; t += 256) {
        int j4 = t * 4;
        int p = j4 / DD;
        int rem = j4 - p * DD;
        int hh = rem / HDD;
        int d = rem - hh * HDD;
        float4 x = *(const float4*)(src + j4);
        float vv[4];
        if (p == 2) {
            vv[0] = x.x; vv[1] = x.y; vv[2] = x.z; vv[3] = x.w;
        } else {
            bool lo = d < 40;
            int dm = lo ? d : d - 40;
            float4 oth = *(const float4*)(src + p * DD + hh * HDD + (lo ? d + 40 : d - 40));
            float4 c4 = *(const float4*)&cs[dm];
            float4 s4 = *(const float4*)&sn[dm];
            float sg = lo ? -1.f : 1.f;
            vv[0] = x.x * c4.x + sg * oth.x * s4.x;
            vv[1] = x.y * c4.y + sg * oth.y * s4.y;
            vv[2] = x.z * c4.z + sg * oth.z * s4.z;
            vv[3] = x.w * c4.w + sg * oth.w * s4.w;
            if (p == 0) { vv[0] *= scale; vv[1] *= scale; vv[2] *= scale; vv[3] *= scale; }
        }
        short* dst = (p == 0) ? q : (p == 1) ? k : v;
        s16x4 o4;
        o4[0] = f2bf(vv[0]); o4[1] = f2bf(vv[1]);
        o4[2] = f2bf(vv[2]); o4[3] = f2bf(vv[3]);
        *(s16x4*)(dst + ((size_t)hh * SS + s) * HDD + d) = o4;
    }
}

// ---- flash attention: 8 waves x 16 q-rows, z=2 ----
// R17 delta (swapped QK^T, T12-style): s_ = mfma(K_frag, Q_frag) puts
// q at l15 and k at quad*4+r -> consecutive k's are LANE-LOCAL:
//  * P->bf16 via v_cvt_pk_bf16_f32 (8 ops, was 16 f2bf = 48 ops)
//  * Ps write = 8 ds_write_b32 (was 16 ds_write_b16)
//  * lsum is a scalar (reduce = 2 shfl_xor over quads)
// Ps read side (pf = P[q=l15][k-octet]) already matches -> unchanged.
// Keeps R16 async-stage dbuf + setprio.
__global__ __launch_bounds__(512, 4) void attn_mfma(
    const short* __restrict__ q, const short* __restrict__ k,
    const short* __restrict__ v, _Float16* __restrict__ o_part,
    float* __restrict__ l_part)
{
    __shared__ short Ks[2][64][104];   // keys x dims (pad cols 80..95 zeroed)
    __shared__ short Vts[2][80 * 64];  // dims x keys, XOR-swizzled octets
    __shared__ short Ps[8][16 * 64];   // per-wave P tile, XOR octet swizzle

    const int h = blockIdx.y;
    const int q0 = blockIdx.x << 7;   // 128 rows per block
    const int z = blockIdx.z;
    const int tid = threadIdx.x;
    const int w = tid >> 6;           // 0..7
    const int lane = tid & 63;
    const int l15 = lane & 15;
    const int quad = lane >> 4;

    const short* qbase = q + (size_t)h * SS * HDD;
    const short* kbase = k + (size_t)h * SS * HDD;
    const short* vbase = v + (size_t)h * SS * HDD;

    short8 qf[3];
    {
        const int row = q0 + w * 16 + l15;
        #pragma unroll
        for (int kk = 0; kk < 3; ++kk) {
            int c0 = kk * 32 + quad * 8;
            qf[kk] = (c0 < HDD) ? *(const short8*)(qbase + (size_t)row * HDD + c0)
                                : (short8)0;
        }
    }

    if (tid < 256) {   // zero K pad cols 80..95 in BOTH buffers (never rewritten)
        int b = tid >> 7;
        int t2 = tid & 127;
        int r = t2 >> 1, c = 80 + (t2 & 1) * 8;
        *(short8*)&Ks[b][r][c] = (short8)0;
    }

    float lsum = 0.f;
    f32x4 o[5];
    #pragma unroll
    for (int n = 0; n < 5; ++n) o[n] = (f32x4){0.f, 0.f, 0.f, 0.f};

    // ---- async-stage state: K (2x short8), V (4x s16x4) ----
    short8 kr[2];
    s16x4 vr[4];
    auto issueKV = [&](int kt) {
        #pragma unroll
        for (int u = 0; u < 2; ++u) {
            int i = tid + u * 512;
            if (i < 640) {
                int r = i / 10, c = (i - r * 10) * 8;
                kr[u] = *(const short8*)(kbase + (size_t)(kt + r) * HDD + c);
            }
        }
        if (tid < 320) {
            int r4 = (tid & 15) << 2, d4 = (tid >> 4) << 2;
            #pragma unroll
            for (int j = 0; j < 4; ++j)
                vr[j] = *(const s16x4*)(vbase + (size_t)(kt + r4 + j) * HDD + d4);
        }
    };
    auto writeKV = [&](int buf) {
        #pragma unroll
        for (int u = 0; u < 2; ++u) {
            int i = tid + u * 512;
            if (i < 640) {
                int r = i / 10, c = (i - r * 10) * 8;
                *(short8*)&Ks[buf][r][c] = kr[u];
            }
        }
        if (tid < 320) {
            int r4 = (tid & 15) << 2, d4 = (tid >> 4) << 2;
            #pragma unroll
            for (int j = 0; j < 4; ++j) {
                s16x4 w4 = {vr[0][j], vr[1][j], vr[2][j], vr[3][j]};
                int d = d4 + j;
                int sw = (r4 >> 3) ^ (d & 7);
                *(s16x4*)&Vts[buf][d * 64 + sw * 8 + (r4 & 7)] = w4;
            }
        }
    };

    const int kt0 = z << 10;          // 1024 kv rows per z-slice
    issueKV(kt0);
    writeKV(0);
    __syncthreads();
    int cur = 0;
    for (int t = 0; t < 16; ++t) {
        const int kt = kt0 + t * 64;
        const bool more = (t + 1 < 16);
        if (more) issueKV(kt + 64);    // VMEM in flight across compute

        f32x4 s_[4];
        __builtin_amdgcn_s_setprio(1);
        #pragma unroll
        for (int nt = 0; nt < 4; ++nt) {
            short8 bf0 = *(short8*)&Ks[cur][nt * 16 + l15][quad * 8];
            short8 bf1 = *(short8*)&Ks[cur][nt * 16 + l15][32 + quad * 8];
            short8 bf2 = *(short8*)&Ks[cur][nt * 16 + l15][64 + quad * 8];
            f32x4 acc = (f32x4){0.f, 0.f, 0.f, 0.f};
            // swapped operands: output is S^T -> lane holds q=l15, k=quad*4+r
            acc = __builtin_amdgcn_mfma_f32_16x16x32_bf16(bf0, qf[0], acc, 0, 0, 0);
            acc = __builtin_amdgcn_mfma_f32_16x16x32_bf16(bf1, qf[1], acc, 0, 0, 0);
            acc = __builtin_amdgcn_mfma_f32_16x16x32_bf16(bf2, qf[2], acc, 0, 0, 0);
            s_[nt] = acc;
        }
        __builtin_amdgcn_s_setprio(0);

        // softmax: p = exp(S - 8); k is lane-local -> pack pairs, 8 dword writes.
        // Ps layout unchanged: row=q, phys col octet g = (k>>3)^(q&7).
        #pragma unroll
        for (int nt = 0; nt < 4; ++nt)
            #pragma unroll
            for (int r2 = 0; r2 < 2; ++r2) {
                float p0 = __expf(s_[nt][2 * r2]     - 8.f);
                float p1 = __expf(s_[nt][2 * r2 + 1] - 8.f);
                lsum += p0 + p1;
                int pk;
                asm("v_cvt_pk_bf16_f32 %0, %1, %2" : "=v"(pk) : "v"(p0), "v"(p1));
                int col = nt * 16 + quad * 4 + 2 * r2;
                int g = (col >> 3) ^ (l15 & 7);
                *(int*)&Ps[w][l15 * 64 + g * 8 + (col & 7)] = pk;
            }

        short8 pf[2];
        #pragma unroll
        for (int kk = 0; kk < 2; ++kk) {
            int g = (kk * 4 + quad) ^ (l15 & 7);
            pf[kk] = *(short8*)&Ps[w][l15 * 64 + g * 8];
        }
        __builtin_amdgcn_s_setprio(1);
        #pragma unroll
        for (int n = 0; n < 5; ++n) {
            #pragma unroll
            for (int kk = 0; kk < 2; ++kk) {
                int d = n * 16 + l15;
                int sw = (kk * 4 + quad) ^ (l15 & 7);
                short8 vf = *(short8*)&Vts[cur][d * 64 + sw * 8];
                o[n] = __builtin_amdgcn_mfma_f32_16x16x32_bf16(pf[kk], vf, o[n], 0, 0, 0);
            }
        }
        __builtin_amdgcn_s_setprio(0);

        if (more) writeKV(cur ^ 1);    // vmcnt naturally resolved by now
        __syncthreads();               // buf[cur^1] visible; reads of buf[cur] done
        cur ^= 1;
    }

    _Float16* ob = o_part + (size_t)z * SS * DD;
    {   // reduce lsum over quads: lanes differ only in k-partials
        lsum += __shfl_xor(lsum, 16, 64);
        lsum += __shfl_xor(lsum, 32, 64);
    }
    #pragma unroll
    for (int n = 0; n < 5; ++n)
        #pragma unroll
        for (int r = 0; r < 4; ++r) {
            int row = q0 + w * 16 + quad * 4 + r;
            ob[(size_t)row * DD + h * HDD + n * 16 + l15] = (_Float16)o[n][r];
        }
    if (quad == 0)
        l_part[((size_t)z * HH + h) * SS + q0 + w * 16 + l15] = lsum;

}

extern "C" void kernel_launch(void* const* d_in, const int* in_sizes, int n_in,
                              void* d_out, int out_size, void* d_ws, size_t ws_size,
                              hipStream_t stream)
{
    const float* hs     = (const float*)d_in[0];
    const float* rpe    = (const float*)d_in[1];
    const float* qkv_w  = (const float*)d_in[2];
    const float* qkv_b  = (const float*)d_in[3];
    const float* proj_w = (const float*)d_in[4];
    const float* proj_b = (const float*)d_in[5];
    float* out = (float*)d_out;

    // ---- workspace layout (55.7 MB, region-aliased; 2-byte units) ----
    short* s0 = (short*)d_ws;                   // R0: 15,728,640 units
    float* qkv_f  = (float*)d_ws;               //   [S][3D] fp32, dead after rope
    _Float16* o_part = (_Float16*)s0;           //   R0 reuse: ZZ x S x D fp16 partials
    float* l_part = (float*)(s0 + 10485760);    //   ZZ x H x S fp32
    short* s1 = s0 + 15728640;                  // R1: 7,864,320 units
    _Float16* qkvw_h = (_Float16*)s1;           //   dead after gemm1
    short* qb = s1;                             //   R1 reuse after gemm1
    short* kb = s1 + 2621440;
    short* vb = s1 + 5242880;
    short* s2 = s1 + 7864320;                   // R2: 2,621,440 units
    _Float16* hs_h = (_Float16*)s2;
    short* s3 = s2 + 2621440;                   // R3: 1,638,400 units
    _Float16* projw_h = (_Float16*)s3;

    const int n_hs = SS * DD;        // 2,621,440 -> 2560 blocks
    const int n_qw = ND3 * DD;       // 4,915,200 -> 4800 blocks
    const int n_pw = DD * DD;        // 1,638,400 -> 1600 blocks

    split_f16<<<n_hs / 1024 + n_qw / 1024 + n_pw / 1024, 256, 0, stream>>>(
        hs, hs_h, n_hs / 1024,
        qkv_w, qkvw_h, n_qw / 1024,
        proj_w, projw_h);
    gemm_f16<128, 128><<<dim3(ND3 / 128, SS / 128), 256, 0, stream>>>(
        hs_h, qkvw_h, qkv_b, qkv_f, SS, ND3, DD);
    rope_scatter_bf16<<<SS, 256, 0, stream>>>(qkv_f, rpe, qb, kb, vb);
    attn_mfma<<<dim3(SS / 128, HH, ZZ), 512, 0, stream>>>(qb, kb, vb, o_part, l_part);
    gemm_proj_merge<<<dim3(DD / 128, SS / 64), 256, 0, stream>>>(
        o_part, l_part, projw_h, proj_b, out, SS, DD, DD);
}

// Round 10
// 204.049 us; speedup vs baseline: 1.0477x; 1.0102x over previous
//
#include <hip/hip_runtime.h>
#include <math.h>

#define SS 2048
#define DD 1280
#define HH 16
#define HDD 80
#define ND3 3840
#define ZZ 2   // K-split factor for attention partials

typedef __attribute__((ext_vector_type(8))) short short8;
typedef __attribute__((ext_vector_type(4))) short s16x4;
typedef __attribute__((ext_vector_type(4))) float f32x4;
typedef __attribute__((ext_vector_type(8))) _Float16 h16x8;
typedef __attribute__((ext_vector_type(4))) _Float16 h16x4;

__device__ inline short f2bf(float f) {
    union { float f; unsigned u; } x; x.f = f;
    unsigned r = x.u + 0x7FFF + ((x.u >> 16) & 1);
    return (short)(r >> 16);
}

// direct global->LDS 16B staging (m97 pattern). LDS dest must be the
// wave-uniform base; HW adds lane*16.
__device__ inline void gload_lds16(const void* g, void* l) {
    __builtin_amdgcn_global_load_lds(
        (const __attribute__((address_space(1))) void*)g,
        (__attribute__((address_space(3))) void*)l, 16, 0, 0);
}

// ---------------- fused convert: three fp32 arrays -> fp16 ----------------
__global__ __launch_bounds__(256) void split_f16(
    const float* __restrict__ a, _Float16* __restrict__ ah, int nbA,
    const float* __restrict__ b, _Float16* __restrict__ bh, int nbB,
    const float* __restrict__ c, _Float16* __restrict__ ch)
{
    const float* x; _Float16* h;
    int blk = blockIdx.x;
    if (blk < nbA)            { x = a; h = ah; }
    else if (blk < nbA + nbB) { blk -= nbA; x = b; h = bh; }
    else                      { blk -= nbA + nbB; x = c; h = ch; }
    int i = (blk * 256 + threadIdx.x) * 4;
    float4 v = *(const float4*)(x + i);
    h16x4 hv;
    hv[0] = (_Float16)v.x; hv[1] = (_Float16)v.y;
    hv[2] = (_Float16)v.z; hv[3] = (_Float16)v.w;
    *(h16x4*)(h + i) = hv;
}

#define LDSA(m, kg) ((m) * 32 + (((kg) ^ (((m) >> 1) & 3)) << 3))

// ---------------- fp16 MFMA GEMM: C(fp16) = A @ B^T + bias (R15 2-phase) ----
// R19: C output is fp16 (halves qkv intermediate write+read traffic; fp16
// rel-err 4.9e-4 << the bf16 cast rope already applies).
template <int BMT, int BNT>
__global__ __launch_bounds__(256) void gemm_f16(
    const _Float16* __restrict__ Ah, const _Float16* __restrict__ Bh,
    const float* __restrict__ bias, _Float16* __restrict__ C,
    int M, int N, int K)
{
    constexpr int IT = BMT / 32;
    constexpr int JT = BNT / 32;
    constexpr int AU = BMT / 64;
    constexpr int BU = BNT / 64;
    __shared__ _Float16 AhS[2][BMT * 32];
    __shared__ _Float16 BhS[2][BNT * 32];

    const int tid = threadIdx.x;
    const int w = tid >> 6;
    const int lane = tid & 63;
    const int l15 = lane & 15;
    const int quad = lane >> 4;
    const int wm = w >> 1, wn = w & 1;
    const int bm = blockIdx.y * BMT;
    const int bn = blockIdx.x * BNT;

    f32x4 acc[IT][JT];
    #pragma unroll
    for (int i = 0; i < IT; ++i)
        #pragma unroll
        for (int j = 0; j < JT; ++j)
            acc[i][j] = (f32x4){0.f, 0.f, 0.f, 0.f};

    auto stage = [&](int buf, int k0) {
        #pragma unroll
        for (int u = 0; u < AU; ++u) {
            int i = tid + u * 256;
            int m = i >> 2;
            int kg = (i & 3) ^ ((m >> 1) & 3);
            gload_lds16(Ah + (size_t)(bm + m) * K + k0 + kg * 8,
                        &AhS[buf][(i & ~63) * 8]);
        }
        #pragma unroll
        for (int u = 0; u < BU; ++u) {
            int i = tid + u * 256;
            int m = i >> 2;
            int kg = (i & 3) ^ ((m >> 1) & 3);
            gload_lds16(Bh + (size_t)(bn + m) * K + k0 + kg * 8,
                        &BhS[buf][(i & ~63) * 8]);
        }
    };

    stage(0, 0);
    __syncthreads();            // drain prologue stage
    int cur = 0;
    for (int k0 = 0; k0 < K; k0 += 32) {
        if (k0 + 32 < K) stage(cur ^ 1, k0 + 32);   // issue next, no wait

        h16x8 af[IT], bf[JT];
        #pragma unroll
        for (int i = 0; i < IT; ++i) {
            int m = wm * (BMT / 2) + i * 16 + l15;
            af[i] = *(h16x8*)&AhS[cur][LDSA(m, quad)];
        }
        #pragma unroll
        for (int j = 0; j < JT; ++j) {
            int n = wn * (BNT / 2) + j * 16 + l15;
            bf[j] = *(h16x8*)&BhS[cur][LDSA(n, quad)];
        }
        #pragma unroll
        for (int i = 0; i < IT; ++i)
            #pragma unroll
            for (int j = 0; j < JT; ++j)
                acc[i][j] = __builtin_amdgcn_mfma_f32_16x16x32_f16(af[i], bf[j], acc[i][j], 0, 0, 0);

        __syncthreads();        // drains vmcnt(0): next tile now resident
        cur ^= 1;
    }

    #pragma unroll
    for (int j = 0; j < JT; ++j) {
        int col = bn + wn * (BNT / 2) + j * 16 + l15;
        float bb = bias[col];
        #pragma unroll
        for (int i = 0; i < IT; ++i)
            #pragma unroll
            for (int r = 0; r < 4; ++r) {
                int row = bm + wm * (BMT / 2) + i * 16 + quad * 4 + r;
                C[(size_t)row * N + col] = (_Float16)(acc[i][j][r] + bb);
            }
    }
}

// ---- proj GEMM with fused attention-merge in A-staging (R15 2-phase B) ----
__global__ __launch_bounds__(256) void gemm_proj_merge(
    const _Float16* __restrict__ o_part, const float* __restrict__ l_part,
    const _Float16* __restrict__ Bh,
    const float* __restrict__ bias, float* __restrict__ C,
    int M, int N, int K)
{
    constexpr int BMT = 64, BNT = 128;
    constexpr int JT = BNT / 32;
    constexpr int BU = BNT / 64;
    __shared__ _Float16 AhS[BMT * 32];
    __shared__ _Float16 BhS[2][BNT * 32];
    __shared__ float linvS[HH * 64];

    const int tid = threadIdx.x;
    const int w = tid >> 6;
    const int lane = tid & 63;
    const int l15 = lane & 15;
    const int quad = lane >> 4;
    const int wm = w >> 1, wn = w & 1;
    const int bm = blockIdx.y * BMT;
    const int bn = blockIdx.x * BNT;

    // build inv-l table: 16 heads x 64 rows, summed over ZZ partials
    for (int i = tid; i < HH * 64; i += 256) {
        int h = i >> 6, r = i & 63;
        float ls = 0.f;
        #pragma unroll
        for (int zi = 0; zi < ZZ; ++zi)
            ls += l_part[((size_t)zi * HH + h) * SS + bm + r];
        linvS[i] = 1.f / ls;
    }

    f32x4 acc[2][JT];
    #pragma unroll
    for (int i = 0; i < 2; ++i)
        #pragma unroll
        for (int j = 0; j < JT; ++j)
            acc[i][j] = (f32x4){0.f, 0.f, 0.f, 0.f};

    h16x8 ra[ZZ];
    auto loadgA = [&](int k0) {
        int m = tid >> 2, kg = tid & 3;
        size_t off = (size_t)(bm + m) * K + k0 + kg * 8;
        #pragma unroll
        for (int zi = 0; zi < ZZ; ++zi)
            ra[zi] = *(const h16x8*)(o_part + (size_t)zi * SS * DD + off);
    };
    auto stageB = [&](int buf, int k0) {
        #pragma unroll
        for (int u = 0; u < BU; ++u) {
            int i = tid + u * 256;
            int m = i >> 2;
            int kg = (i & 3) ^ ((m >> 1) & 3);
            gload_lds16(Bh + (size_t)(bn + m) * K + k0 + kg * 8,
                        &BhS[buf][(i & ~63) * 8]);
        }
    };

    stageB(0, 0);
    loadgA(0);
    __syncthreads();            // linv + B0 resident
    int cur = 0;
    for (int k0 = 0; k0 < K; k0 += 32) {
        {   // merge A partials -> fp16 LDS (consumes prefetched ra)
            int m = tid >> 2, kg = tid & 3;
            int koff = k0 + kg * 8;
            int h = koff / HDD;                 // 8-elem chunk stays in one head
            float inv = linvS[h * 64 + m];
            h16x8 f;
            #pragma unroll
            for (int e = 0; e < 8; ++e) {
                float s = (float)ra[0][e];
                #pragma unroll
                for (int zi = 1; zi < ZZ; ++zi) s += (float)ra[zi][e];
                f[e] = (_Float16)(s * inv);
            }
            *(h16x8*)&AhS[LDSA(m, kg)] = f;
        }
        __syncthreads();        // A visible (no pending async B yet)

        if (k0 + 32 < K) {
            stageB(cur ^ 1, k0 + 32);   // async, flies during MFMA
            loadgA(k0 + 32);            // reg prefetch, flies during MFMA
        }

        h16x8 af[2], bf[JT];
        #pragma unroll
        for (int i = 0; i < 2; ++i) {
            int m = wm * 32 + i * 16 + l15;
            af[i] = *(h16x8*)&AhS[LDSA(m, quad)];
        }
        #pragma unroll
        for (int j = 0; j < JT; ++j) {
            int n = wn * 64 + j * 16 + l15;
            bf[j] = *(h16x8*)&BhS[cur][LDSA(n, quad)];
        }
        #pragma unroll
        for (int i = 0; i < 2; ++i)
            #pragma unroll
            for (int j = 0; j < JT; ++j)
                acc[i][j] = __builtin_amdgcn_mfma_f32_16x16x32_f16(af[i], bf[j], acc[i][j], 0, 0, 0);

        __syncthreads();        // drains next-B loads; frees AhS + BhS[cur]
        cur ^= 1;
    }

    #pragma unroll
    for (int j = 0; j < JT; ++j) {
        int col = bn + wn * 64 + j * 16 + l15;
        float bb = bias[col];
        #pragma unroll
        for (int i = 0; i < 2; ++i)
            #pragma unroll
            for (int r = 0; r < 4; ++r) {
                int row = bm + wm * 32 + i * 16 + quad * 4 + r;
                C[(size_t)row * N + col] = acc[i][j][r] + bb;
            }
    }
}

// ---------------- RoPE + scatter, 4-wide vectorized (fp16 input) ----------
__global__ __launch_bounds__(256) void rope_scatter_bf16(
    const _Float16* __restrict__ qkv, const float* __restrict__ rpe,
    short* __restrict__ q, short* __restrict__ k, short* __restrict__ v)
{
    __shared__ __align__(16) float cs[40], sn[40];
    const int s = blockIdx.x;
    if (threadIdx.x < 40)
        __sincosf(rpe[s * 40 + threadIdx.x], &sn[threadIdx.x], &cs[threadIdx.x]);
    __syncthreads();
    const float scale = 0.11180339887498949f;  // 80^-0.5
    const _Float16* src = qkv + (size_t)s * ND3;
    for (int t = threadIdx.x; t < ND3 / 4; t += 256) {
        int j4 = t * 4;
        int p = j4 / DD;
        int rem = j4 - p * DD;
        int hh = rem / HDD;
        int d = rem - hh * HDD;
        h16x4 xh = *(const h16x4*)(src + j4);
        float vv[4];
        if (p == 2) {
            vv[0] = (float)xh[0]; vv[1] = (float)xh[1];
            vv[2] = (float)xh[2]; vv[3] = (float)xh[3];
        } else {
            bool lo = d < 40;
            int dm = lo ? d : d - 40;
            h16x4 oh = *(const h16x4*)(src + p * DD + hh * HDD + (lo ? d + 40 : d - 40));
            float4 c4 = *(const float4*)&cs[dm];
            float4 s4 = *(const float4*)&sn[dm];
            float sg = lo ? -1.f : 1.f;
            vv[0] = (float)xh[0] * c4.x + sg * (float)oh[0] * s4.x;
            vv[1] = (float)xh[1] * c4.y + sg * (float)oh[1] * s4.y;
            vv[2] = (float)xh[2] * c4.z + sg * (float)oh[2] * s4.z;
            vv[3] = (float)xh[3] * c4.w + sg * (float)oh[3] * s4.w;
            if (p == 0) { vv[0] *= scale; vv[1] *= scale; vv[2] *= scale; vv[3] *= scale; }
        }
        short* dst = (p == 0) ? q : (p == 1) ? k : v;
        s16x4 o4;
        o4[0] = f2bf(vv[0]); o4[1] = f2bf(vv[1]);
        o4[2] = f2bf(vv[2]); o4[3] = f2bf(vv[3]);
        *(s16x4*)(dst + ((size_t)hh * SS + s) * HDD + d) = o4;
    }
}

// ---- flash attention: 8 waves x 16 q-rows, z=2 (R17, known-good) ----
// R18's single-buffered-Ks schedule FAILED correctness (absmax 476, race
// not identifiable by inspection) -> reverted to R17 exactly. Occupancy is
// grid-capped at 2 blocks/CU anyway (512 blocks / 256 CU), so the LDS
// shrink had no payoff to justify the risk.
__global__ __launch_bounds__(512, 4) void attn_mfma(
    const short* __restrict__ q, const short* __restrict__ k,
    const short* __restrict__ v, _Float16* __restrict__ o_part,
    float* __restrict__ l_part)
{
    __shared__ short Ks[2][64][104];   // keys x dims (pad cols 80..95 zeroed)
    __shared__ short Vts[2][80 * 64];  // dims x keys, XOR-swizzled octets
    __shared__ short Ps[8][16 * 64];   // per-wave P tile, XOR octet swizzle

    const int h = blockIdx.y;
    const int q0 = blockIdx.x << 7;   // 128 rows per block
    const int z = blockIdx.z;
    const int tid = threadIdx.x;
    const int w = tid >> 6;           // 0..7
    const int lane = tid & 63;
    const int l15 = lane & 15;
    const int quad = lane >> 4;

    const short* qbase = q + (size_t)h * SS * HDD;
    const short* kbase = k + (size_t)h * SS * HDD;
    const short* vbase = v + (size_t)h * SS * HDD;

    short8 qf[3];
    {
        const int row = q0 + w * 16 + l15;
        #pragma unroll
        for (int kk = 0; kk < 3; ++kk) {
            int c0 = kk * 32 + quad * 8;
            qf[kk] = (c0 < HDD) ? *(const short8*)(qbase + (size_t)row * HDD + c0)
                                : (short8)0;
        }
    }

    if (tid < 256) {   // zero K pad cols 80..95 in BOTH buffers (never rewritten)
        int b = tid >> 7;
        int t2 = tid & 127;
        int r = t2 >> 1, c = 80 + (t2 & 1) * 8;
        *(short8*)&Ks[b][r][c] = (short8)0;
    }

    float lsum = 0.f;
    f32x4 o[5];
    #pragma unroll
    for (int n = 0; n < 5; ++n) o[n] = (f32x4){0.f, 0.f, 0.f, 0.f};

    // ---- async-stage state: K (2x short8), V (4x s16x4) ----
    short8 kr[2];
    s16x4 vr[4];
    auto issueKV = [&](int kt) {
        #pragma unroll
        for (int u = 0; u < 2; ++u) {
            int i = tid + u * 512;
            if (i < 640) {
                int r = i / 10, c = (i - r * 10) * 8;
                kr[u] = *(const short8*)(kbase + (size_t)(kt + r) * HDD + c);
            }
        }
        if (tid < 320) {
            int r4 = (tid & 15) << 2, d4 = (tid >> 4) << 2;
            #pragma unroll
            for (int j = 0; j < 4; ++j)
                vr[j] = *(const s16x4*)(vbase + (size_t)(kt + r4 + j) * HDD + d4);
        }
    };
    auto writeKV = [&](int buf) {
        #pragma unroll
        for (int u = 0; u < 2; ++u) {
            int i = tid + u * 512;
            if (i < 640) {
                int r = i / 10, c = (i - r * 10) * 8;
                *(short8*)&Ks[buf][r][c] = kr[u];
            }
        }
        if (tid < 320) {
            int r4 = (tid & 15) << 2, d4 = (tid >> 4) << 2;
            #pragma unroll
            for (int j = 0; j < 4; ++j) {
                s16x4 w4 = {vr[0][j], vr[1][j], vr[2][j], vr[3][j]};
                int d = d4 + j;
                int sw = (r4 >> 3) ^ (d & 7);
                *(s16x4*)&Vts[buf][d * 64 + sw * 8 + (r4 & 7)] = w4;
            }
        }
    };

    const int kt0 = z << 10;          // 1024 kv rows per z-slice
    issueKV(kt0);
    writeKV(0);
    __syncthreads();
    int cur = 0;
    for (int t = 0; t < 16; ++t) {
        const int kt = kt0 + t * 64;
        const bool more = (t + 1 < 16);
        if (more) issueKV(kt + 64);    // VMEM in flight across compute

        f32x4 s_[4];
        __builtin_amdgcn_s_setprio(1);
        #pragma unroll
        for (int nt = 0; nt < 4; ++nt) {
            short8 bf0 = *(short8*)&Ks[cur][nt * 16 + l15][quad * 8];
            short8 bf1 = *(short8*)&Ks[cur][nt * 16 + l15][32 + quad * 8];
            short8 bf2 = *(short8*)&Ks[cur][nt * 16 + l15][64 + quad * 8];
            f32x4 acc = (f32x4){0.f, 0.f, 0.f, 0.f};
            // swapped operands: output is S^T -> lane holds q=l15, k=quad*4+r
            acc = __builtin_amdgcn_mfma_f32_16x16x32_bf16(bf0, qf[0], acc, 0, 0, 0);
            acc = __builtin_amdgcn_mfma_f32_16x16x32_bf16(bf1, qf[1], acc, 0, 0, 0);
            acc = __builtin_amdgcn_mfma_f32_16x16x32_bf16(bf2, qf[2], acc, 0, 0, 0);
            s_[nt] = acc;
        }
        __builtin_amdgcn_s_setprio(0);

        // softmax: p = exp(S - 8); k is lane-local -> pack pairs, 8 dword writes.
        // Ps layout unchanged: row=q, phys col octet g = (k>>3)^(q&7).
        #pragma unroll
        for (int nt = 0; nt < 4; ++nt)
            #pragma unroll
            for (int r2 = 0; r2 < 2; ++r2) {
                float p0 = __expf(s_[nt][2 * r2]     - 8.f);
                float p1 = __expf(s_[nt][2 * r2 + 1] - 8.f);
                lsum += p0 + p1;
                int pk;
                asm("v_cvt_pk_bf16_f32 %0, %1, %2" : "=v"(pk) : "v"(p0), "v"(p1));
                int col = nt * 16 + quad * 4 + 2 * r2;
                int g = (col >> 3) ^ (l15 & 7);
                *(int*)&Ps[w][l15 * 64 + g * 8 + (col & 7)] = pk;
            }

        short8 pf[2];
        #pragma unroll
        for (int kk = 0; kk < 2; ++kk) {
            int g = (kk * 4 + quad) ^ (l15 & 7);
            pf[kk] = *(short8*)&Ps[w][l15 * 64 + g * 8];
        }
        __builtin_amdgcn_s_setprio(1);
        #pragma unroll
        for (int n = 0; n < 5; ++n) {
            #pragma unroll
            for (int kk = 0; kk < 2; ++kk) {
                int d = n * 16 + l15;
                int sw = (kk * 4 + quad) ^ (l15 & 7);
                short8 vf = *(short8*)&Vts[cur][d * 64 + sw * 8];
                o[n] = __builtin_amdgcn_mfma_f32_16x16x32_bf16(pf[kk], vf, o[n], 0, 0, 0);
            }
        }
        __builtin_amdgcn_s_setprio(0);

        if (more) writeKV(cur ^ 1);    // vmcnt naturally resolved by now
        __syncthreads();               // buf[cur^1] visible; reads of buf[cur] done
        cur ^= 1;
    }

    _Float16* ob = o_part + (size_t)z * SS * DD;
    {   // reduce lsum over quads: lanes differ only in k-partials
        lsum += __shfl_xor(lsum, 16, 64);
        lsum += __shfl_xor(lsum, 32, 64);
    }
    #pragma unroll
    for (int n = 0; n < 5; ++n)
        #pragma unroll
        for (int r = 0; r < 4; ++r) {
            int row = q0 + w * 16 + quad * 4 + r;
            ob[(size_t)row * DD + h * HDD + n * 16 + l15] = (_Float16)o[n][r];
        }
    if (quad == 0)
        l_part[((size_t)z * HH + h) * SS + q0 + w * 16 + l15] = lsum;

}

extern "C" void kernel_launch(void* const* d_in, const int* in_sizes, int n_in,
                              void* d_out, int out_size, void* d_ws, size_t ws_size,
                              hipStream_t stream)
{
    const float* hs     = (const float*)d_in[0];
    const float* rpe    = (const float*)d_in[1];
    const float* qkv_w  = (const float*)d_in[2];
    const float* qkv_b  = (const float*)d_in[3];
    const float* proj_w = (const float*)d_in[4];
    const float* proj_b = (const float*)d_in[5];
    float* out = (float*)d_out;

    // ---- workspace layout (55.7 MB, region-aliased; 2-byte units) ----
    short* s0 = (short*)d_ws;                   // R0: 15,728,640 units
    _Float16* qkv_f = (_Float16*)d_ws;          //   [S][3D] fp16, dead after rope
    _Float16* o_part = (_Float16*)s0;           //   R0 reuse: ZZ x S x D fp16 partials
    float* l_part = (float*)(s0 + 10485760);    //   ZZ x H x S fp32
    short* s1 = s0 + 15728640;                  // R1: 7,864,320 units
    _Float16* qkvw_h = (_Float16*)s1;           //   dead after gemm1
    short* qb = s1;                             //   R1 reuse after gemm1
    short* kb = s1 + 2621440;
    short* vb = s1 + 5242880;
    short* s2 = s1 + 7864320;                   // R2: 2,621,440 units
    _Float16* hs_h = (_Float16*)s2;
    short* s3 = s2 + 2621440;                   // R3: 1,638,400 units
    _Float16* projw_h = (_Float16*)s3;

    const int n_hs = SS * DD;        // 2,621,440 -> 2560 blocks
    const int n_qw = ND3 * DD;       // 4,915,200 -> 4800 blocks
    const int n_pw = DD * DD;        // 1,638,400 -> 1600 blocks

    split_f16<<<n_hs / 1024 + n_qw / 1024 + n_pw / 1024, 256, 0, stream>>>(
        hs, hs_h, n_hs / 1024,
        qkv_w, qkvw_h, n_qw / 1024,
        proj_w, projw_h);
    gemm_f16<128, 128><<<dim3(ND3 / 128, SS / 128), 256, 0, stream>>>(
        hs_h, qkvw_h, qkv_b, qkv_f, SS, ND3, DD);
    rope_scatter_bf16<<<SS, 256, 0, stream>>>(qkv_f, rpe, qb, kb, vb);
    attn_mfma<<<dim3(SS / 128, HH, ZZ), 512, 0, stream>>>(qb, kb, vb, o_part, l_part);
    gemm_proj_merge<<<dim3(DD / 128, SS / 64), 256, 0, stream>>>(
        o_part, l_part, projw_h, proj_b, out, SS, DD, DD);
}